// Round 17
// baseline (1797.027 us; speedup 1.0000x reference)
//
#include <hip/hip_runtime.h>
#include <math.h>

#define NTOK 131072
#define HDIM 256
#define DDIM 512
#define FDIM 1024
#define EDIM 16
#define TBLK 128
#define FCH  64
#define KST  32
#define XST  40    // f16 LDS row stride (80 B)
#define HST  68    // f32 LDS row stride (272 B)

// d_ws layout (bytes):
//  xh tiled  @0          : 131072*512 f16 = 134217728
//  xl tiled  @134217728  : 134217728
//  w1h frag  @268435456  : 512*1024 f16 = 1048576
//  w1l frag  @269484032  : 1048576      -> total 270532608
#define WS_XL  134217728ULL
#define WS_W1H 268435456ULL
#define WS_W1L 269484032ULL
#define WS_NEED 270532608ULL

typedef __attribute__((ext_vector_type(8))) _Float16 v8h;
typedef __attribute__((ext_vector_type(4))) _Float16 v4h;
typedef __attribute__((ext_vector_type(4))) float v4f;

__device__ __forceinline__ void f2h2(float v, _Float16& h, _Float16& l) {
    h = (_Float16)v;
    l = (_Float16)(v - (float)h);
}

__device__ __forceinline__ void pack8(const float* u, v8h& hh, v8h& hl) {
    _Float16 h0,l0,h1,l1,h2,l2,h3,l3,h4,l4,h5,l5,h6,l6,h7,l7;
    f2h2(u[0],h0,l0); f2h2(u[1],h1,l1); f2h2(u[2],h2,l2); f2h2(u[3],h3,l3);
    f2h2(u[4],h4,l4); f2h2(u[5],h5,l5); f2h2(u[6],h6,l6); f2h2(u[7],h7,l7);
    hh[0]=h0; hh[1]=h1; hh[2]=h2; hh[3]=h3; hh[4]=h4; hh[5]=h5; hh[6]=h6; hh[7]=h7;
    hl[0]=l0; hl[1]=l1; hl[2]=l2; hl[3]=l3; hl[4]=l4; hl[5]=l5; hl[6]=l6; hl[7]=l7;
}

// x -> f16 hi/lo, tile-contiguous: tile(tb,st) = [128 tok][32 k] = 4096 f16.
__global__ __launch_bounds__(256, 4)
void prep_x(const float* __restrict__ inp, const float* __restrict__ cnd,
            _Float16* __restrict__ xh, _Float16* __restrict__ xl)
{
    const size_t g  = (size_t)blockIdx.x * 256 + threadIdx.x;   // 0..8388607
    const size_t o8 = g * 8;
    const int tile = (int)(o8 >> 12);
    const int e    = (int)(o8 & 4095);
    const int tb = tile >> 4, st = tile & 15;
    const int row = e >> 5, kcol = e & 31;
    const int tok = tb * TBLK + row;
    const int k   = st * KST + kcol;
    const float* src = (k < HDIM) ? (inp + (size_t)tok * HDIM + k)
                                  : (cnd + (size_t)tok * HDIM + (k - HDIM));
    float u[8];
    *(float4*)&u[0] = *(const float4*)(src);
    *(float4*)&u[4] = *(const float4*)(src + 4);
    v8h hh, hl;
    pack8(u, hh, hl);
    *(v8h*)(xh + o8) = hh;
    *(v8h*)(xl + o8) = hl;
}

// W1 -> f16 hi/lo in MFMA B-fragment order:
// slot g: lane=g&63, K=(g>>6)&15, F=g>>10; f=F*16+(lane&15); k=K*32+(lane>>4)*8+e
__global__ __launch_bounds__(256, 4)
void prep_w1(const float* __restrict__ W1,
             _Float16* __restrict__ wh, _Float16* __restrict__ wl)
{
    const int g = blockIdx.x * 256 + threadIdx.x;   // 0..65535
    const int lane = g & 63;
    const int K = (g >> 6) & 15;
    const int F = g >> 10;
    const int f  = F * 16 + (lane & 15);
    const int kb = K * KST + (lane >> 4) * 8;
    float u[8];
#pragma unroll
    for (int e = 0; e < 8; ++e)
        u[e] = W1[(size_t)(kb + e) * FDIM + f];
    v8h hh, hl;
    pack8(u, hh, hl);
    *(v8h*)(wh + (size_t)g * 8) = hh;
    *(v8h*)(wl + (size_t)g * 8) = hl;
}

// Main: R15 structure, conversion-free staging (x from tiled ws),
// B-fragments streamed from L2-resident frag array (no W1 LDS).
// LDS 34816 B: xs_h[128][40] @0, xs_l @10240; hs f32 [128][68] aliases @0.
__global__ __launch_bounds__(256, 2)
void router_mfma9(const _Float16* __restrict__ xh, const _Float16* __restrict__ xl,
                  const _Float16* __restrict__ w1h, const _Float16* __restrict__ w1l,
                  const float* __restrict__ b1,
                  const float* __restrict__ W2,
                  const float* __restrict__ b2,
                  float* __restrict__ out)
{
    __shared__ __align__(16) char smem[34816];
    _Float16* xs_h = (_Float16*)(smem);
    _Float16* xs_l = (_Float16*)(smem + 10240);
    float*    hs   = (float*)(smem);          // alias, barrier-separated

    const int tid  = threadIdx.x;
    const int lane = tid & 63;
    const int w    = tid >> 6;
    const int wr   = w >> 1;          // token half (64)
    const int wc   = w & 1;           // F half (32 of the 64-chunk)
    const int l15  = lane & 15;
    const int l4   = lane >> 4;
    const int t0   = blockIdx.x * TBLK;
    const int ty   = tid >> 4;
    const int tx   = tid & 15;
    const int r0   = tid >> 2;            // staging row (0..63)
    const int kc0  = (tid & 3) * 8;       // staging k-oct

    float lg[8];
    {
        const float bb = b2[tx];
#pragma unroll
        for (int i = 0; i < 8; ++i) lg[i] = bb;
    }

    for (int fc = 0; fc < FDIM; fc += FCH) {
        v4f acc[4][2];
#pragma unroll
        for (int mf = 0; mf < 4; ++mf)
#pragma unroll
            for (int nf = 0; nf < 2; ++nf)
                acc[mf][nf] = (v4f){0.f,0.f,0.f,0.f};

        for (int st = 0; st < 16; ++st) {
            __syncthreads();   // prior MFMA xs reads / prior GEMM2 hs reads done
            // ---- stage x tile: pure copy, fully coalesced (tile-contiguous) ----
            {
                const _Float16* sh = xh + ((size_t)blockIdx.x * 16 + st) * 4096;
                const _Float16* sl = xl + ((size_t)blockIdx.x * 16 + st) * 4096;
                const v8h a0 = *(const v8h*)(sh + tid * 8);
                const v8h a1 = *(const v8h*)(sh + tid * 8 + 2048);
                const v8h b0 = *(const v8h*)(sl + tid * 8);
                const v8h b1v_ = *(const v8h*)(sl + tid * 8 + 2048);
                *(v8h*)(xs_h + r0 * XST + kc0) = a0;
                *(v8h*)(xs_h + (64 + r0) * XST + kc0) = a1;
                *(v8h*)(xs_l + r0 * XST + kc0) = b0;
                *(v8h*)(xs_l + (64 + r0) * XST + kc0) = b1v_;
            }
            __syncthreads();
            // ---- MFMA 16x16x32 f16: A from LDS, B streamed from frag array ----
            {
#pragma unroll
                for (int nf = 0; nf < 2; ++nf) {
                    const int Fidx = (fc >> 4) + 2 * wc + nf;
                    const size_t boff = (((size_t)Fidx * 16 + st) * 64 + lane) * 8;
                    const v8h bh = *(const v8h*)(w1h + boff);
                    const v8h bl = *(const v8h*)(w1l + boff);
#pragma unroll
                    for (int mf = 0; mf < 4; ++mf) {
                        const int aoff = (64 * wr + 16 * mf + l15) * XST + 8 * l4;
                        const v8h ah = *(const v8h*)(xs_h + aoff);
                        const v8h al = *(const v8h*)(xs_l + aoff);
                        acc[mf][nf] = __builtin_amdgcn_mfma_f32_16x16x32_f16(ah, bh, acc[mf][nf], 0, 0, 0);
                        acc[mf][nf] = __builtin_amdgcn_mfma_f32_16x16x32_f16(al, bh, acc[mf][nf], 0, 0, 0);
                        acc[mf][nf] = __builtin_amdgcn_mfma_f32_16x16x32_f16(ah, bl, acc[mf][nf], 0, 0, 0);
                    }
                }
            }
        }
        __syncthreads();   // all MFMA xs reads done; hs may alias

        // ---- bias + exact GELU -> hs (f32) ----
        {
            float b1v[2];
#pragma unroll
            for (int nf = 0; nf < 2; ++nf)
                b1v[nf] = b1[fc + 32 * wc + 16 * nf + l15];
#pragma unroll
            for (int mf = 0; mf < 4; ++mf)
#pragma unroll
                for (int nf = 0; nf < 2; ++nf)
#pragma unroll
                    for (int r = 0; r < 4; ++r) {
                        const float v = acc[mf][nf][r] + b1v[nf];
                        const int tok  = 64 * wr + 16 * mf + 4 * l4 + r;
                        const int fcol = 32 * wc + 16 * nf + l15;
                        hs[tok * HST + fcol]
                            = 0.5f * v * (1.0f + erff(v * 0.70710678118654752f));
                    }
        }
        __syncthreads();

        // ---- GEMM2: direct per-expert dot, jb staggered by l4 (R15-proven) ----
#pragma unroll
        for (int jb = 0; jb < 16; ++jb) {
            const int jbs = (jb + 4 * l4) & 15;
            float w2v[4];
#pragma unroll
            for (int j = 0; j < 4; ++j)
                w2v[j] = W2[(size_t)(fc + jbs * 4 + j) * EDIM + tx];
#pragma unroll
            for (int i = 0; i < 8; ++i) {
                const float4 hv = *(const float4*)(hs + (ty * 8 + i) * HST + jbs * 4);
                lg[i] = fmaf(hv.x, w2v[0], lg[i]);
                lg[i] = fmaf(hv.y, w2v[1], lg[i]);
                lg[i] = fmaf(hv.z, w2v[2], lg[i]);
                lg[i] = fmaf(hv.w, w2v[3], lg[i]);
            }
        }
    }

    // ---- softmax + clip + top-2 + writes (R4-proven) ----
#pragma unroll
    for (int i = 0; i < 8; ++i) {
        const int t = t0 + ty * 8 + i;
        float mx = lg[i];
#pragma unroll
        for (int m = 1; m < 16; m <<= 1) mx = fmaxf(mx, __shfl_xor(mx, m, 64));
        float p = expf(lg[i] - mx);
        float s = p;
#pragma unroll
        for (int m = 1; m < 16; m <<= 1) s += __shfl_xor(s, m, 64);
        float pr = p / s;
        pr = fminf(fmaxf(pr, 1e-9f), 1.0f - 1e-9f);

        float v1 = pr; int i1 = tx;
#pragma unroll
        for (int m = 1; m < 16; m <<= 1) {
            const float vo = __shfl_xor(v1, m, 64);
            const int   io = __shfl_xor(i1, m, 64);
            if (vo > v1 || (vo == v1 && io < i1)) { v1 = vo; i1 = io; }
        }
        float v2 = (tx == i1) ? -1.0f : pr; int i2 = tx;
#pragma unroll
        for (int m = 1; m < 16; m <<= 1) {
            const float vo = __shfl_xor(v2, m, 64);
            const int   io = __shfl_xor(i2, m, 64);
            if (vo > v2 || (vo == v2 && io < i2)) { v2 = vo; i2 = io; }
        }
        const float rs = 1.0f / (v1 + v2);

        float* om  = out + (size_t)t * EDIM;
        float* orp = out + (size_t)NTOK * 18 + (size_t)t * EDIM;
        float* opf = out + (size_t)NTOK * 34 + (size_t)t * EDIM;
        om[tx]  = (tx == i1 || tx == i2) ? 1.0f : 0.0f;
        orp[tx] = (tx == i1) ? v1 * rs : ((tx == i2) ? v2 * rs : 0.0f);
        opf[tx] = pr;
        if (tx == 0) {
            float2* oi = (float2*)(out + (size_t)NTOK * 16 + (size_t)t * 2);
            *oi = make_float2((float)i1, (float)i2);
        }
    }
}

// ---------------- R15 fallback (verbatim), used if ws too small ----------------
__global__ __launch_bounds__(256, 2)
void router_mfma7(const float* __restrict__ inp,
                  const float* __restrict__ cnd,
                  const float* __restrict__ W1,
                  const float* __restrict__ b1,
                  const float* __restrict__ W2,
                  const float* __restrict__ b2,
                  float* __restrict__ out)
{
    __shared__ __align__(16) char smem[34816];
    _Float16* xs_h = (_Float16*)(smem);
    _Float16* xs_l = (_Float16*)(smem + 10240);
    _Float16* ws_h = (_Float16*)(smem + 20480);
    _Float16* ws_l = (_Float16*)(smem + 25600);
    float*    hs   = (float*)(smem);

    const int tid  = threadIdx.x;
    const int lane = tid & 63;
    const int w    = tid >> 6;
    const int wr   = w >> 1;
    const int wc   = w & 1;
    const int l15  = lane & 15;
    const int l4   = lane >> 4;
    const int t0   = blockIdx.x * TBLK;
    const int ty   = tid >> 4;
    const int tx   = tid & 15;
    const int kq   = tid & 7;
    const int xr   = tid >> 3;
    const int fcl  = tid & 63;
    const int kg   = tid >> 6;

    float lg[8];
    { const float bb = b2[tx];
#pragma unroll
      for (int i = 0; i < 8; ++i) lg[i] = bb; }

    for (int fc = 0; fc < FDIM; fc += FCH) {
        v4f acc[4][2];
#pragma unroll
        for (int mf = 0; mf < 4; ++mf)
#pragma unroll
            for (int nf = 0; nf < 2; ++nf) acc[mf][nf] = (v4f){0.f,0.f,0.f,0.f};

        for (int st = 0; st < 16; ++st) {
            const int kc = st * KST;
            __syncthreads();
            {
                const float* src = (kc < HDIM) ? (inp + (size_t)t0 * HDIM + kc)
                                               : (cnd + (size_t)t0 * HDIM + (kc - HDIM));
#pragma unroll
                for (int p = 0; p < 4; ++p) {
                    const int row = xr + 32 * p;
                    const float4 v = *(const float4*)(src + (size_t)row * HDIM + kq * 4);
                    _Float16 h0,l0,h1,l1,h2,l2,h3,l3;
                    f2h2(v.x,h0,l0); f2h2(v.y,h1,l1); f2h2(v.z,h2,l2); f2h2(v.w,h3,l3);
                    v4h hh, hl;
                    hh[0]=h0; hh[1]=h1; hh[2]=h2; hh[3]=h3;
                    hl[0]=l0; hl[1]=l1; hl[2]=l2; hl[3]=l3;
                    *(v4h*)(xs_h + row * XST + kq * 4) = hh;
                    *(v4h*)(xs_l + row * XST + kq * 4) = hl;
                }
            }
#pragma unroll
            for (int s = 0; s < 2; ++s) {
                const int kb = 4 * kg + 16 * s;
                const float u0 = W1[(size_t)(kc + kb + 0) * FDIM + fc + fcl];
                const float u1 = W1[(size_t)(kc + kb + 1) * FDIM + fc + fcl];
                const float u2 = W1[(size_t)(kc + kb + 2) * FDIM + fc + fcl];
                const float u3 = W1[(size_t)(kc + kb + 3) * FDIM + fc + fcl];
                _Float16 h0,l0,h1,l1,h2,l2,h3,l3;
                f2h2(u0,h0,l0); f2h2(u1,h1,l1); f2h2(u2,h2,l2); f2h2(u3,h3,l3);
                v4h hh, hl;
                hh[0]=h0; hh[1]=h1; hh[2]=h2; hh[3]=h3;
                hl[0]=l0; hl[1]=l1; hl[2]=l2; hl[3]=l3;
                *(v4h*)(ws_h + fcl * XST + kb) = hh;
                *(v4h*)(ws_l + fcl * XST + kb) = hl;
            }
            __syncthreads();
            {
                v8h bh[2], bl[2];
#pragma unroll
                for (int nf = 0; nf < 2; ++nf) {
                    const int off = (32 * wc + 16 * nf + l15) * XST + 8 * l4;
                    bh[nf] = *(const v8h*)(ws_h + off);
                    bl[nf] = *(const v8h*)(ws_l + off);
                }
#pragma unroll
                for (int mf = 0; mf < 4; ++mf) {
                    const int off = (64 * wr + 16 * mf + l15) * XST + 8 * l4;
                    const v8h ah = *(const v8h*)(xs_h + off);
                    const v8h al = *(const v8h*)(xs_l + off);
#pragma unroll
                    for (int nf = 0; nf < 2; ++nf) {
                        acc[mf][nf] = __builtin_amdgcn_mfma_f32_16x16x32_f16(ah, bh[nf], acc[mf][nf], 0, 0, 0);
                        acc[mf][nf] = __builtin_amdgcn_mfma_f32_16x16x32_f16(al, bh[nf], acc[mf][nf], 0, 0, 0);
                        acc[mf][nf] = __builtin_amdgcn_mfma_f32_16x16x32_f16(ah, bl[nf], acc[mf][nf], 0, 0, 0);
                    }
                }
            }
        }
        __syncthreads();
        {
            float b1v[2];
#pragma unroll
            for (int nf = 0; nf < 2; ++nf) b1v[nf] = b1[fc + 32 * wc + 16 * nf + l15];
#pragma unroll
            for (int mf = 0; mf < 4; ++mf)
#pragma unroll
                for (int nf = 0; nf < 2; ++nf)
#pragma unroll
                    for (int r = 0; r < 4; ++r) {
                        const float v = acc[mf][nf][r] + b1v[nf];
                        const int tok  = 64 * wr + 16 * mf + 4 * l4 + r;
                        const int fcol = 32 * wc + 16 * nf + l15;
                        hs[tok * HST + fcol] = 0.5f * v * (1.0f + erff(v * 0.70710678118654752f));
                    }
        }
        __syncthreads();
#pragma unroll
        for (int jb = 0; jb < 16; ++jb) {
            const int jbs = (jb + 4 * l4) & 15;
            float w2v[4];
#pragma unroll
            for (int j = 0; j < 4; ++j)
                w2v[j] = W2[(size_t)(fc + jbs * 4 + j) * EDIM + tx];
#pragma unroll
            for (int i = 0; i < 8; ++i) {
                const float4 hv = *(const float4*)(hs + (ty * 8 + i) * HST + jbs * 4);
                lg[i] = fmaf(hv.x, w2v[0], lg[i]);
                lg[i] = fmaf(hv.y, w2v[1], lg[i]);
                lg[i] = fmaf(hv.z, w2v[2], lg[i]);
                lg[i] = fmaf(hv.w, w2v[3], lg[i]);
            }
        }
    }
#pragma unroll
    for (int i = 0; i < 8; ++i) {
        const int t = t0 + ty * 8 + i;
        float mx = lg[i];
#pragma unroll
        for (int m = 1; m < 16; m <<= 1) mx = fmaxf(mx, __shfl_xor(mx, m, 64));
        float p = expf(lg[i] - mx);
        float s = p;
#pragma unroll
        for (int m = 1; m < 16; m <<= 1) s += __shfl_xor(s, m, 64);
        float pr = p / s;
        pr = fminf(fmaxf(pr, 1e-9f), 1.0f - 1e-9f);
        float v1 = pr; int i1 = tx;
#pragma unroll
        for (int m = 1; m < 16; m <<= 1) {
            const float vo = __shfl_xor(v1, m, 64);
            const int   io = __shfl_xor(i1, m, 64);
            if (vo > v1 || (vo == v1 && io < i1)) { v1 = vo; i1 = io; }
        }
        float v2 = (tx == i1) ? -1.0f : pr; int i2 = tx;
#pragma unroll
        for (int m = 1; m < 16; m <<= 1) {
            const float vo = __shfl_xor(v2, m, 64);
            const int   io = __shfl_xor(i2, m, 64);
            if (vo > v2 || (vo == v2 && io < i2)) { v2 = vo; i2 = io; }
        }
        const float rs = 1.0f / (v1 + v2);
        float* om  = out + (size_t)t * EDIM;
        float* orp = out + (size_t)NTOK * 18 + (size_t)t * EDIM;
        float* opf = out + (size_t)NTOK * 34 + (size_t)t * EDIM;
        om[tx]  = (tx == i1 || tx == i2) ? 1.0f : 0.0f;
        orp[tx] = (tx == i1) ? v1 * rs : ((tx == i2) ? v2 * rs : 0.0f);
        opf[tx] = pr;
        if (tx == 0) {
            float2* oi = (float2*)(out + (size_t)NTOK * 16 + (size_t)t * 2);
            *oi = make_float2((float)i1, (float)i2);
        }
    }
}

extern "C" void kernel_launch(void* const* d_in, const int* in_sizes, int n_in,
                              void* d_out, int out_size, void* d_ws, size_t ws_size,
                              hipStream_t stream)
{
    const float* inp = (const float*)d_in[0];
    const float* cnd = (const float*)d_in[1];
    const float* W1  = (const float*)d_in[2];
    const float* b1  = (const float*)d_in[3];
    const float* W2  = (const float*)d_in[4];
    const float* b2  = (const float*)d_in[5];
    float* out = (float*)d_out;

    if (ws_size >= WS_NEED) {
        char* wsb = (char*)d_ws;
        _Float16* xh  = (_Float16*)(wsb);
        _Float16* xl  = (_Float16*)(wsb + WS_XL);
        _Float16* w1h = (_Float16*)(wsb + WS_W1H);
        _Float16* w1l = (_Float16*)(wsb + WS_W1L);
        hipLaunchKernelGGL(prep_x, dim3(32768), dim3(256), 0, stream, inp, cnd, xh, xl);
        hipLaunchKernelGGL(prep_w1, dim3(256), dim3(256), 0, stream, W1, w1h, w1l);
        hipLaunchKernelGGL(router_mfma9, dim3(NTOK / TBLK), dim3(256), 0, stream,
                           xh, xl, w1h, w1l, b1, W2, b2, out);
    } else {
        hipLaunchKernelGGL(router_mfma7, dim3(NTOK / TBLK), dim3(256), 0, stream,
                           inp, cnd, W1, b1, W2, b2, out);
    }
}

// Round 18
// 751.187 us; speedup vs baseline: 2.3922x; 2.3922x over previous
//
#include <hip/hip_runtime.h>
#include <math.h>

#define NTOK 131072
#define HDIM 256
#define DDIM 512
#define FDIM 1024
#define EDIM 16
#define TBLK 128
#define FCH  64
#define KST  32
#define HSS  68    // hs f16 row stride (136 B)

// d_ws layout (bytes):
//  xh frag-tiles @0          : 131072*512 f16 = 134217728
//  xl            @134217728  : 134217728
//  w1h frags     @268435456  : 1048576
//  w1l frags     @269484032  : 1048576     -> 270532608 total
#define WS_XL   134217728ULL
#define WS_W1H  268435456ULL
#define WS_W1L  269484032ULL
#define WS_NEED 270532608ULL

typedef __attribute__((ext_vector_type(8))) _Float16 v8h;
typedef __attribute__((ext_vector_type(4))) _Float16 v4h;
typedef __attribute__((ext_vector_type(4))) float v4f;

__device__ __forceinline__ void f2h2(float v, _Float16& h, _Float16& l) {
    h = (_Float16)v;
    l = (_Float16)(v - (float)h);
}

__device__ __forceinline__ void pack8(const float* u, v8h& hh, v8h& hl) {
    _Float16 h0,l0,h1,l1,h2,l2,h3,l3,h4,l4,h5,l5,h6,l6,h7,l7;
    f2h2(u[0],h0,l0); f2h2(u[1],h1,l1); f2h2(u[2],h2,l2); f2h2(u[3],h3,l3);
    f2h2(u[4],h4,l4); f2h2(u[5],h5,l5); f2h2(u[6],h6,l6); f2h2(u[7],h7,l7);
    hh[0]=h0; hh[1]=h1; hh[2]=h2; hh[3]=h3; hh[4]=h4; hh[5]=h5; hh[6]=h6; hh[7]=h7;
    hl[0]=l0; hl[1]=l1; hl[2]=l2; hl[3]=l3; hl[4]=l4; hl[5]=l5; hl[6]=l6; hl[7]=l7;
}

// x -> f16 hi/lo in MFMA-A-fragment tile order:
// tile T=(tb,st): [frag g 0..7][lane 0..63][e 0..7];
// tok = tb*128 + g*16 + (lane&15); k = st*32 + (lane>>4)*8 + e
__global__ __launch_bounds__(256, 4)
void prep_x(const float* __restrict__ inp, const float* __restrict__ cnd,
            _Float16* __restrict__ xh, _Float16* __restrict__ xl)
{
    const size_t g = (size_t)blockIdx.x * 256 + threadIdx.x;   // 0..8388607
    const int lane = (int)(g & 63);
    const int fg   = (int)((g >> 6) & 7);
    const int T    = (int)(g >> 9);
    const int tb = T >> 4, st = T & 15;
    const int tok = tb * TBLK + fg * 16 + (lane & 15);
    const int k   = st * KST + (lane >> 4) * 8;
    const float* src = (k < HDIM) ? (inp + (size_t)tok * HDIM + k)
                                  : (cnd + (size_t)tok * HDIM + (k - HDIM));
    float u[8];
    *(float4*)&u[0] = *(const float4*)(src);
    *(float4*)&u[4] = *(const float4*)(src + 4);
    v8h hh, hl;
    pack8(u, hh, hl);
    *(v8h*)(xh + g * 8) = hh;
    *(v8h*)(xl + g * 8) = hl;
}

// W1 -> f16 hi/lo in MFMA-B-fragment order:
// slot g: lane=g&63, K=(g>>6)&15, F=g>>10; f=F*16+(lane&15); k=K*32+(lane>>4)*8+e
__global__ __launch_bounds__(256, 4)
void prep_w1(const float* __restrict__ W1,
             _Float16* __restrict__ wh, _Float16* __restrict__ wl)
{
    const int g = blockIdx.x * 256 + threadIdx.x;   // 0..65535
    const int lane = g & 63;
    const int K = (g >> 6) & 15;
    const int F = g >> 10;
    const int f  = F * 16 + (lane & 15);
    const int kb = K * KST + (lane >> 4) * 8;
    float u[8];
#pragma unroll
    for (int e = 0; e < 8; ++e)
        u[e] = W1[(size_t)(kb + e) * FDIM + f];
    v8h hh, hl;
    pack8(u, hh, hl);
    *(v8h*)(wh + (size_t)g * 8) = hh;
    *(v8h*)(wl + (size_t)g * 8) = hl;
}

// Main: R15 skeleton; staging = pure 16B copies (frag order, conflict-free);
// GEMM2 = MFMA with f16 hi/lo hs (R9-validated numerics/epilogue).
// LDS 34816: xs_h[4096]f16 @0 (8192B), xs_l @8192, ws_h[2048] @16384 (4096B),
// ws_l @20480; GEMM2 phase: hs_h[128][68] @0 (17408), hs_l @17408 (alias).
__global__ __launch_bounds__(256, 2)
void router_mfma10(const _Float16* __restrict__ xh, const _Float16* __restrict__ xl,
                   const _Float16* __restrict__ w1h, const _Float16* __restrict__ w1l,
                   const float* __restrict__ b1,
                   const float* __restrict__ W2,
                   const float* __restrict__ b2,
                   float* __restrict__ out)
{
    __shared__ __align__(16) char smem[34816];
    _Float16* xs_h = (_Float16*)(smem);
    _Float16* xs_l = (_Float16*)(smem + 8192);
    _Float16* ws_h = (_Float16*)(smem + 16384);
    _Float16* ws_l = (_Float16*)(smem + 20480);
    _Float16* hs_h = (_Float16*)(smem);            // alias, barrier-separated
    _Float16* hs_l = (_Float16*)(smem + 17408);

    const int tid  = threadIdx.x;
    const int lane = tid & 63;
    const int w    = tid >> 6;        // wave 0..3
    const int wr   = w >> 1;          // token half (64)
    const int wc   = w & 1;           // F half (32 of the 64-chunk)
    const int l15  = lane & 15;
    const int l4   = lane >> 4;
    const int t0   = blockIdx.x * TBLK;

    const float b2v = b2[l15];
    v4f accL[2] = {{0.f,0.f,0.f,0.f},{0.f,0.f,0.f,0.f}};

    for (int fc = 0; fc < FDIM; fc += FCH) {
        v4f acc[4][2];
#pragma unroll
        for (int mf = 0; mf < 4; ++mf)
#pragma unroll
            for (int nf = 0; nf < 2; ++nf)
                acc[mf][nf] = (v4f){0.f,0.f,0.f,0.f};

        for (int st = 0; st < 16; ++st) {
            __syncthreads();   // prior MFMA xs/ws reads or GEMM2 hs reads done
            // ---- stage x tile: pure copy, frag order (conflict-free) ----
            {
                const v8h* sh = (const v8h*)(xh + ((size_t)blockIdx.x * 16 + st) * 4096);
                const v8h* sl = (const v8h*)(xl + ((size_t)blockIdx.x * 16 + st) * 4096);
                ((v8h*)xs_h)[tid]       = sh[tid];
                ((v8h*)xs_h)[tid + 256] = sh[tid + 256];
                ((v8h*)xs_l)[tid]       = sl[tid];
                ((v8h*)xs_l)[tid + 256] = sl[tid + 256];
            }
            // ---- stage W1 B-frags (4 frags x 64 lanes x 8): pure copy ----
            {
                const size_t wb = (((size_t)((fc >> 4) + (tid >> 6)) * 16 + st) * 64
                                   + (tid & 63)) * 8;
                ((v8h*)ws_h)[tid] = *(const v8h*)(w1h + wb);
                ((v8h*)ws_l)[tid] = *(const v8h*)(w1l + wb);
            }
            __syncthreads();
            // ---- MFMA 16x16x32 f16, 3 terms into one accumulator ----
            {
                v8h bh[2], bl[2];
#pragma unroll
                for (int nf = 0; nf < 2; ++nf) {
                    const int off = ((2 * wc + nf) * 64 + lane) * 8;
                    bh[nf] = *(const v8h*)(ws_h + off);
                    bl[nf] = *(const v8h*)(ws_l + off);
                }
#pragma unroll
                for (int mf = 0; mf < 4; ++mf) {
                    const int aoff = ((4 * wr + mf) * 64 + lane) * 8;
                    const v8h ah = *(const v8h*)(xs_h + aoff);
                    const v8h al = *(const v8h*)(xs_l + aoff);
#pragma unroll
                    for (int nf = 0; nf < 2; ++nf) {
                        acc[mf][nf] = __builtin_amdgcn_mfma_f32_16x16x32_f16(ah, bh[nf], acc[mf][nf], 0, 0, 0);
                        acc[mf][nf] = __builtin_amdgcn_mfma_f32_16x16x32_f16(al, bh[nf], acc[mf][nf], 0, 0, 0);
                        acc[mf][nf] = __builtin_amdgcn_mfma_f32_16x16x32_f16(ah, bl[nf], acc[mf][nf], 0, 0, 0);
                    }
                }
            }
        }
        __syncthreads();   // all MFMA xs/ws reads done; hs may alias

        // ---- bias + exact GELU -> hs (f16 hi/lo, stride 68) ----
        {
            float b1v[2];
#pragma unroll
            for (int nf = 0; nf < 2; ++nf)
                b1v[nf] = b1[fc + 32 * wc + 16 * nf + l15];
#pragma unroll
            for (int mf = 0; mf < 4; ++mf)
#pragma unroll
                for (int nf = 0; nf < 2; ++nf)
#pragma unroll
                    for (int r = 0; r < 4; ++r) {
                        const float v = acc[mf][nf][r] + b1v[nf];
                        const float gl = 0.5f * v * (1.0f + erff(v * 0.70710678118654752f));
                        _Float16 hh, hl;
                        f2h2(gl, hh, hl);
                        const int tok  = 64 * wr + 16 * mf + 4 * l4 + r;
                        const int fcol = 32 * wc + 16 * nf + l15;
                        hs_h[tok * HSS + fcol] = hh;
                        hs_l[tok * HSS + fcol] = hl;
                    }
        }
        __syncthreads();

        // ---- GEMM2: MFMA, K=64 per fc chunk (R9-validated scheme) ----
#pragma unroll
        for (int ks = 0; ks < 2; ++ks) {
            v8h vbh, vbl;
#pragma unroll
            for (int j = 0; j < 8; ++j) {
                const float u = W2[(size_t)(fc + 32 * ks + 8 * l4 + j) * EDIM + l15];
                _Float16 hh, hl;
                f2h2(u, hh, hl);
                vbh[j] = hh; vbl[j] = hl;
            }
#pragma unroll
            for (int mf2 = 0; mf2 < 2; ++mf2) {
                const int aoff = (32 * w + 16 * mf2 + l15) * HSS + 32 * ks + 8 * l4;
                const v8h vah = *(const v8h*)(hs_h + aoff);
                const v8h val = *(const v8h*)(hs_l + aoff);
                accL[mf2] = __builtin_amdgcn_mfma_f32_16x16x32_f16(vah, vbh, accL[mf2], 0, 0, 0);
                accL[mf2] = __builtin_amdgcn_mfma_f32_16x16x32_f16(val, vbh, accL[mf2], 0, 0, 0);
                accL[mf2] = __builtin_amdgcn_mfma_f32_16x16x32_f16(vah, vbl, accL[mf2], 0, 0, 0);
            }
        }
        // next fc pass's first staging barrier protects hs
    }

    // ---- softmax + clip + top-2 + writes (R9-proven mapping) ----
    float lg[8];
#pragma unroll
    for (int mf2 = 0; mf2 < 2; ++mf2)
#pragma unroll
        for (int r = 0; r < 4; ++r)
            lg[mf2 * 4 + r] = accL[mf2][r] + b2v;

    const int tx = l15;
#pragma unroll
    for (int i = 0; i < 8; ++i) {
        const int t = t0 + 32 * w + 16 * (i >> 2) + 4 * l4 + (i & 3);
        float mx = lg[i];
#pragma unroll
        for (int m = 1; m < 16; m <<= 1) mx = fmaxf(mx, __shfl_xor(mx, m, 64));
        float p = expf(lg[i] - mx);
        float s = p;
#pragma unroll
        for (int m = 1; m < 16; m <<= 1) s += __shfl_xor(s, m, 64);
        float pr = p / s;
        pr = fminf(fmaxf(pr, 1e-9f), 1.0f - 1e-9f);

        float v1 = pr; int i1 = tx;
#pragma unroll
        for (int m = 1; m < 16; m <<= 1) {
            const float vo = __shfl_xor(v1, m, 64);
            const int   io = __shfl_xor(i1, m, 64);
            if (vo > v1 || (vo == v1 && io < i1)) { v1 = vo; i1 = io; }
        }
        float v2 = (tx == i1) ? -1.0f : pr; int i2 = tx;
#pragma unroll
        for (int m = 1; m < 16; m <<= 1) {
            const float vo = __shfl_xor(v2, m, 64);
            const int   io = __shfl_xor(i2, m, 64);
            if (vo > v2 || (vo == v2 && io < i2)) { v2 = vo; i2 = io; }
        }
        const float rs = 1.0f / (v1 + v2);

        float* om  = out + (size_t)t * EDIM;
        float* orp = out + (size_t)NTOK * 18 + (size_t)t * EDIM;
        float* opf = out + (size_t)NTOK * 34 + (size_t)t * EDIM;
        om[tx]  = (tx == i1 || tx == i2) ? 1.0f : 0.0f;
        orp[tx] = (tx == i1) ? v1 * rs : ((tx == i2) ? v2 * rs : 0.0f);
        opf[tx] = pr;
        if (tx == 0) {
            float2* oi = (float2*)(out + (size_t)NTOK * 16 + (size_t)t * 2);
            *oi = make_float2((float)i1, (float)i2);
        }
    }
}

// ---------------- R15 fallback (verbatim), used if ws too small ----------------
#define XST  40
#define HST  68
__global__ __launch_bounds__(256, 2)
void router_mfma7(const float* __restrict__ inp,
                  const float* __restrict__ cnd,
                  const float* __restrict__ W1,
                  const float* __restrict__ b1,
                  const float* __restrict__ W2,
                  const float* __restrict__ b2,
                  float* __restrict__ out)
{
    __shared__ __align__(16) char smem[34816];
    _Float16* xs_h = (_Float16*)(smem);
    _Float16* xs_l = (_Float16*)(smem + 10240);
    _Float16* ws_h = (_Float16*)(smem + 20480);
    _Float16* ws_l = (_Float16*)(smem + 25600);
    float*    hs   = (float*)(smem);

    const int tid  = threadIdx.x;
    const int lane = tid & 63;
    const int w    = tid >> 6;
    const int wr   = w >> 1;
    const int wc   = w & 1;
    const int l15  = lane & 15;
    const int l4   = lane >> 4;
    const int t0   = blockIdx.x * TBLK;
    const int ty   = tid >> 4;
    const int tx   = tid & 15;
    const int kq   = tid & 7;
    const int xr   = tid >> 3;
    const int fcl  = tid & 63;
    const int kg   = tid >> 6;

    float lg[8];
    { const float bb = b2[tx];
#pragma unroll
      for (int i = 0; i < 8; ++i) lg[i] = bb; }

    for (int fc = 0; fc < FDIM; fc += FCH) {
        v4f acc[4][2];
#pragma unroll
        for (int mf = 0; mf < 4; ++mf)
#pragma unroll
            for (int nf = 0; nf < 2; ++nf) acc[mf][nf] = (v4f){0.f,0.f,0.f,0.f};

        for (int st = 0; st < 16; ++st) {
            const int kc = st * KST;
            __syncthreads();
            {
                const float* src = (kc < HDIM) ? (inp + (size_t)t0 * HDIM + kc)
                                               : (cnd + (size_t)t0 * HDIM + (kc - HDIM));
#pragma unroll
                for (int p = 0; p < 4; ++p) {
                    const int row = xr + 32 * p;
                    const float4 v = *(const float4*)(src + (size_t)row * HDIM + kq * 4);
                    _Float16 h0,l0,h1,l1,h2,l2,h3,l3;
                    f2h2(v.x,h0,l0); f2h2(v.y,h1,l1); f2h2(v.z,h2,l2); f2h2(v.w,h3,l3);
                    v4h hh, hl;
                    hh[0]=h0; hh[1]=h1; hh[2]=h2; hh[3]=h3;
                    hl[0]=l0; hl[1]=l1; hl[2]=l2; hl[3]=l3;
                    *(v4h*)(xs_h + row * XST + kq * 4) = hh;
                    *(v4h*)(xs_l + row * XST + kq * 4) = hl;
                }
            }
#pragma unroll
            for (int s = 0; s < 2; ++s) {
                const int kb = 4 * kg + 16 * s;
                const float u0 = W1[(size_t)(kc + kb + 0) * FDIM + fc + fcl];
                const float u1 = W1[(size_t)(kc + kb + 1) * FDIM + fc + fcl];
                const float u2 = W1[(size_t)(kc + kb + 2) * FDIM + fc + fcl];
                const float u3 = W1[(size_t)(kc + kb + 3) * FDIM + fc + fcl];
                _Float16 h0,l0,h1,l1,h2,l2,h3,l3;
                f2h2(u0,h0,l0); f2h2(u1,h1,l1); f2h2(u2,h2,l2); f2h2(u3,h3,l3);
                v4h hh, hl;
                hh[0]=h0; hh[1]=h1; hh[2]=h2; hh[3]=h3;
                hl[0]=l0; hl[1]=l1; hl[2]=l2; hl[3]=l3;
                *(v4h*)(ws_h + fcl * XST + kb) = hh;
                *(v4h*)(ws_l + fcl * XST + kb) = hl;
            }
            __syncthreads();
            {
                v8h bh[2], bl[2];
#pragma unroll
                for (int nf = 0; nf < 2; ++nf) {
                    const int off = (32 * wc + 16 * nf + l15) * XST + 8 * l4;
                    bh[nf] = *(const v8h*)(ws_h + off);
                    bl[nf] = *(const v8h*)(ws_l + off);
                }
#pragma unroll
                for (int mf = 0; mf < 4; ++mf) {
                    const int off = (64 * wr + 16 * mf + l15) * XST + 8 * l4;
                    const v8h ah = *(const v8h*)(xs_h + off);
                    const v8h al = *(const v8h*)(xs_l + off);
#pragma unroll
                    for (int nf = 0; nf < 2; ++nf) {
                        acc[mf][nf] = __builtin_amdgcn_mfma_f32_16x16x32_f16(ah, bh[nf], acc[mf][nf], 0, 0, 0);
                        acc[mf][nf] = __builtin_amdgcn_mfma_f32_16x16x32_f16(al, bh[nf], acc[mf][nf], 0, 0, 0);
                        acc[mf][nf] = __builtin_amdgcn_mfma_f32_16x16x32_f16(ah, bl[nf], acc[mf][nf], 0, 0, 0);
                    }
                }
            }
        }
        __syncthreads();
        {
            float b1v[2];
#pragma unroll
            for (int nf = 0; nf < 2; ++nf) b1v[nf] = b1[fc + 32 * wc + 16 * nf + l15];
#pragma unroll
            for (int mf = 0; mf < 4; ++mf)
#pragma unroll
                for (int nf = 0; nf < 2; ++nf)
#pragma unroll
                    for (int r = 0; r < 4; ++r) {
                        const float v = acc[mf][nf][r] + b1v[nf];
                        const int tok  = 64 * wr + 16 * mf + 4 * l4 + r;
                        const int fcol = 32 * wc + 16 * nf + l15;
                        hs[tok * HST + fcol] = 0.5f * v * (1.0f + erff(v * 0.70710678118654752f));
                    }
        }
        __syncthreads();
#pragma unroll
        for (int jb = 0; jb < 16; ++jb) {
            const int jbs = (jb + 4 * l4) & 15;
            float w2v[4];
#pragma unroll
            for (int j = 0; j < 4; ++j)
                w2v[j] = W2[(size_t)(fc + jbs * 4 + j) * EDIM + tx];
#pragma unroll
            for (int i = 0; i < 8; ++i) {
                const float4 hv = *(const float4*)(hs + (ty * 8 + i) * HST + jbs * 4);
                lg[i] = fmaf(hv.x, w2v[0], lg[i]);
                lg[i] = fmaf(hv.y, w2v[1], lg[i]);
                lg[i] = fmaf(hv.z, w2v[2], lg[i]);
                lg[i] = fmaf(hv.w, w2v[3], lg[i]);
            }
        }
    }
#pragma unroll
    for (int i = 0; i < 8; ++i) {
        const int t = t0 + ty * 8 + i;
        float mx = lg[i];
#pragma unroll
        for (int m = 1; m < 16; m <<= 1) mx = fmaxf(mx, __shfl_xor(mx, m, 64));
        float p = expf(lg[i] - mx);
        float s = p;
#pragma unroll
        for (int m = 1; m < 16; m <<= 1) s += __shfl_xor(s, m, 64);
        float pr = p / s;
        pr = fminf(fmaxf(pr, 1e-9f), 1.0f - 1e-9f);
        float v1 = pr; int i1 = tx;
#pragma unroll
        for (int m = 1; m < 16; m <<= 1) {
            const float vo = __shfl_xor(v1, m, 64);
            const int   io = __shfl_xor(i1, m, 64);
            if (vo > v1 || (vo == v1 && io < i1)) { v1 = vo; i1 = io; }
        }
        float v2 = (tx == i1) ? -1.0f : pr; int i2 = tx;
#pragma unroll
        for (int m = 1; m < 16; m <<= 1) {
            const float vo = __shfl_xor(v2, m, 64);
            const int   io = __shfl_xor(i2, m, 64);
            if (vo > v2 || (vo == v2 && io < i2)) { v2 = vo; i2 = io; }
        }
        const float rs = 1.0f / (v1 + v2);
        float* om  = out + (size_t)t * EDIM;
        float* orp = out + (size_t)NTOK * 18 + (size_t)t * EDIM;
        float* opf = out + (size_t)NTOK * 34 + (size_t)t * EDIM;
        om[tx]  = (tx == i1 || tx == i2) ? 1.0f : 0.0f;
        orp[tx] = (tx == i1) ? v1 * rs : ((tx == i2) ? v2 * rs : 0.0f);
        opf[tx] = pr;
        if (tx == 0) {
            float2* oi = (float2*)(out + (size_t)NTOK * 16 + (size_t)t * 2);
            *oi = make_float2((float)i1, (float)i2);
        }
    }
}

extern "C" void kernel_launch(void* const* d_in, const int* in_sizes, int n_in,
                              void* d_out, int out_size, void* d_ws, size_t ws_size,
                              hipStream_t stream)
{
    const float* inp = (const float*)d_in[0];
    const float* cnd = (const float*)d_in[1];
    const float* W1  = (const float*)d_in[2];
    const float* b1  = (const float*)d_in[3];
    const float* W2  = (const float*)d_in[4];
    const float* b2  = (const float*)d_in[5];
    float* out = (float*)d_out;

    if (ws_size >= WS_NEED) {
        char* wsb = (char*)d_ws;
        _Float16* xh  = (_Float16*)(wsb);
        _Float16* xl  = (_Float16*)(wsb + WS_XL);
        _Float16* w1h = (_Float16*)(wsb + WS_W1H);
        _Float16* w1l = (_Float16*)(wsb + WS_W1L);
        hipLaunchKernelGGL(prep_x, dim3(32768), dim3(256), 0, stream, inp, cnd, xh, xl);
        hipLaunchKernelGGL(prep_w1, dim3(256), dim3(256), 0, stream, W1, w1h, w1l);
        hipLaunchKernelGGL(router_mfma10, dim3(NTOK / TBLK), dim3(256), 0, stream,
                           xh, xl, w1h, w1l, b1, W2, b2, out);
    } else {
        hipLaunchKernelGGL(router_mfma7, dim3(NTOK / TBLK), dim3(256), 0, stream,
                           inp, cnd, W1, b1, W2, b2, out);
    }
}

// Round 19
// 688.078 us; speedup vs baseline: 2.6117x; 1.0917x over previous
//
#include <hip/hip_runtime.h>
#include <math.h>

#define NTOK 131072
#define HDIM 256
#define DDIM 512
#define FDIM 1024
#define EDIM 16
#define TBLK 128
#define FCH  128
#define KST  32
#define HSS  68    // hs f16 row stride (136 B)

// d_ws layout (bytes): xh frag-tiles @0 (134217728), xl @134217728,
// w1h frags @268435456 (1048576), w1l @269484032 (1048576) -> 270532608
#define WS_XL   134217728ULL
#define WS_W1H  268435456ULL
#define WS_W1L  269484032ULL
#define WS_NEED 270532608ULL

typedef __attribute__((ext_vector_type(8))) _Float16 v8h;
typedef __attribute__((ext_vector_type(4))) _Float16 v4h;
typedef __attribute__((ext_vector_type(4))) float v4f;

__device__ __forceinline__ void f2h2(float v, _Float16& h, _Float16& l) {
    h = (_Float16)v;
    l = (_Float16)(v - (float)h);
}

__device__ __forceinline__ void pack8(const float* u, v8h& hh, v8h& hl) {
    _Float16 h0,l0,h1,l1,h2,l2,h3,l3,h4,l4,h5,l5,h6,l6,h7,l7;
    f2h2(u[0],h0,l0); f2h2(u[1],h1,l1); f2h2(u[2],h2,l2); f2h2(u[3],h3,l3);
    f2h2(u[4],h4,l4); f2h2(u[5],h5,l5); f2h2(u[6],h6,l6); f2h2(u[7],h7,l7);
    hh[0]=h0; hh[1]=h1; hh[2]=h2; hh[3]=h3; hh[4]=h4; hh[5]=h5; hh[6]=h6; hh[7]=h7;
    hl[0]=l0; hl[1]=l1; hl[2]=l2; hl[3]=l3; hl[4]=l4; hl[5]=l5; hl[6]=l6; hl[7]=l7;
}

// x -> f16 hi/lo, MFMA-A-fragment tile order (tile T=(tb,st): [frag][lane][8])
__global__ __launch_bounds__(256, 4)
void prep_x(const float* __restrict__ inp, const float* __restrict__ cnd,
            _Float16* __restrict__ xh, _Float16* __restrict__ xl)
{
    const size_t g = (size_t)blockIdx.x * 256 + threadIdx.x;
    const int lane = (int)(g & 63);
    const int fg   = (int)((g >> 6) & 7);
    const int T    = (int)(g >> 9);
    const int tb = T >> 4, st = T & 15;
    const int tok = tb * TBLK + fg * 16 + (lane & 15);
    const int k   = st * KST + (lane >> 4) * 8;
    const float* src = (k < HDIM) ? (inp + (size_t)tok * HDIM + k)
                                  : (cnd + (size_t)tok * HDIM + (k - HDIM));
    float u[8];
    *(float4*)&u[0] = *(const float4*)(src);
    *(float4*)&u[4] = *(const float4*)(src + 4);
    v8h hh, hl;
    pack8(u, hh, hl);
    *(v8h*)(xh + g * 8) = hh;
    *(v8h*)(xl + g * 8) = hl;
}

// W1 -> f16 hi/lo, MFMA-B-fragment order
__global__ __launch_bounds__(256, 4)
void prep_w1(const float* __restrict__ W1,
             _Float16* __restrict__ wh, _Float16* __restrict__ wl)
{
    const int g = blockIdx.x * 256 + threadIdx.x;
    const int lane = g & 63;
    const int K = (g >> 6) & 15;
    const int F = g >> 10;
    const int f  = F * 16 + (lane & 15);
    const int kb = K * KST + (lane >> 4) * 8;
    float u[8];
#pragma unroll
    for (int e = 0; e < 8; ++e)
        u[e] = W1[(size_t)(kb + e) * FDIM + f];
    v8h hh, hl;
    pack8(u, hh, hl);
    *(v8h*)(wh + (size_t)g * 8) = hh;
    *(v8h*)(wl + (size_t)g * 8) = hl;
}

// Main: R18 structure + FCH=128 (x re-streams 16->8). acc[4][4]=64 VGPR;
// A held per 2-frag group, B streamed (live ~105 < 128 cap).
// GEMM2/GELU: two-half hs scheme (R12-proven), hs f16 hi/lo [128][68].
// LDS 34816: xs_h @0 (8192), xs_l @8192, ws_h @16384 (8192), ws_l @24576;
// GEMM2 phase alias: hs_h @0 (17408), hs_l @17408.
__global__ __launch_bounds__(256, 2)
void router_mfma11(const _Float16* __restrict__ xh, const _Float16* __restrict__ xl,
                   const _Float16* __restrict__ w1h, const _Float16* __restrict__ w1l,
                   const float* __restrict__ b1,
                   const float* __restrict__ W2,
                   const float* __restrict__ b2,
                   float* __restrict__ out)
{
    __shared__ __align__(16) char smem[34816];
    _Float16* xs_h = (_Float16*)(smem);
    _Float16* xs_l = (_Float16*)(smem + 8192);
    _Float16* ws_h = (_Float16*)(smem + 16384);
    _Float16* ws_l = (_Float16*)(smem + 24576);
    _Float16* hs_h = (_Float16*)(smem);            // alias, barrier-separated
    _Float16* hs_l = (_Float16*)(smem + 17408);

    const int tid  = threadIdx.x;
    const int lane = tid & 63;
    const int w    = tid >> 6;        // wave 0..3
    const int wr   = w >> 1;          // token half (64)
    const int wf   = w & 1;           // F half (64 of the 128-chunk)
    const int l15  = lane & 15;
    const int l4   = lane >> 4;
    const int t0   = blockIdx.x * TBLK;

    const float b2v = b2[l15];
    v4f accL[2] = {{0.f,0.f,0.f,0.f},{0.f,0.f,0.f,0.f}};

    for (int fc = 0; fc < FDIM; fc += FCH) {
        v4f acc[4][4];
#pragma unroll
        for (int mf = 0; mf < 4; ++mf)
#pragma unroll
            for (int nf = 0; nf < 4; ++nf)
                acc[mf][nf] = (v4f){0.f,0.f,0.f,0.f};

        for (int st = 0; st < 16; ++st) {
            __syncthreads();   // prior MFMA xs/ws reads or GEMM2 hs reads done
            // ---- stage x tile: pure copy, frag order (conflict-free) ----
            {
                const v8h* sh = (const v8h*)(xh + ((size_t)blockIdx.x * 16 + st) * 4096);
                const v8h* sl = (const v8h*)(xl + ((size_t)blockIdx.x * 16 + st) * 4096);
                ((v8h*)xs_h)[tid]       = sh[tid];
                ((v8h*)xs_h)[tid + 256] = sh[tid + 256];
                ((v8h*)xs_l)[tid]       = sl[tid];
                ((v8h*)xs_l)[tid + 256] = sl[tid + 256];
            }
            // ---- stage W1 B-frags (8 frags): pure copy ----
            {
                const int fr0 = tid >> 6;   // 0..3
                const size_t wb0 = (((size_t)((fc >> 4) + fr0) * 16 + st) * 64 + (tid & 63)) * 8;
                const size_t wb1 = (((size_t)((fc >> 4) + 4 + fr0) * 16 + st) * 64 + (tid & 63)) * 8;
                ((v8h*)ws_h)[tid]       = *(const v8h*)(w1h + wb0);
                ((v8h*)ws_h)[tid + 256] = *(const v8h*)(w1h + wb1);
                ((v8h*)ws_l)[tid]       = *(const v8h*)(w1l + wb0);
                ((v8h*)ws_l)[tid + 256] = *(const v8h*)(w1l + wb1);
            }
            __syncthreads();
            // ---- MFMA 16x16x32 f16: A per 2-frag group resident, B streamed ----
#pragma unroll
            for (int mg = 0; mg < 2; ++mg) {
                v8h ah[2], al[2];
#pragma unroll
                for (int q = 0; q < 2; ++q) {
                    const int aoff = ((4 * wr + 2 * mg + q) * 64 + lane) * 8;
                    ah[q] = *(const v8h*)(xs_h + aoff);
                    al[q] = *(const v8h*)(xs_l + aoff);
                }
#pragma unroll
                for (int nf = 0; nf < 4; ++nf) {
                    const int boff = ((4 * wf + nf) * 64 + lane) * 8;
                    const v8h bh = *(const v8h*)(ws_h + boff);
                    const v8h bl = *(const v8h*)(ws_l + boff);
#pragma unroll
                    for (int q = 0; q < 2; ++q) {
                        acc[2*mg+q][nf] = __builtin_amdgcn_mfma_f32_16x16x32_f16(ah[q], bh, acc[2*mg+q][nf], 0, 0, 0);
                        acc[2*mg+q][nf] = __builtin_amdgcn_mfma_f32_16x16x32_f16(al[q], bh, acc[2*mg+q][nf], 0, 0, 0);
                        acc[2*mg+q][nf] = __builtin_amdgcn_mfma_f32_16x16x32_f16(ah[q], bl, acc[2*mg+q][nf], 0, 0, 0);
                    }
                }
            }
        }
        __syncthreads();   // all MFMA xs/ws reads done; hs may alias

        float b1v[4];
#pragma unroll
        for (int nf = 0; nf < 4; ++nf)
            b1v[nf] = b1[fc + 64 * wf + 16 * nf + l15];

#pragma unroll
        for (int h = 0; h < 2; ++h) {
            // ---- GELU: waves with wf==h write their 64 F cols (local 0..63) ----
            if (wf == h) {
#pragma unroll
                for (int mf = 0; mf < 4; ++mf)
#pragma unroll
                    for (int nf = 0; nf < 4; ++nf)
#pragma unroll
                        for (int r = 0; r < 4; ++r) {
                            const float v = acc[mf][nf][r] + b1v[nf];
                            const float gl = 0.5f * v * (1.0f + erff(v * 0.70710678118654752f));
                            _Float16 hh, hl;
                            f2h2(gl, hh, hl);
                            const int tok  = 64 * wr + 16 * mf + 4 * l4 + r;
                            const int fcol = 16 * nf + l15;   // local 0..63
                            hs_h[tok * HSS + fcol] = hh;
                            hs_l[tok * HSS + fcol] = hl;
                        }
            }
            __syncthreads();
            // ---- GEMM2 half h: MFMA, K=64 (R9/R18-validated scheme) ----
#pragma unroll
            for (int ks = 0; ks < 2; ++ks) {
                v8h vbh, vbl;
#pragma unroll
                for (int j = 0; j < 8; ++j) {
                    const float u = W2[(size_t)(fc + 64 * h + 32 * ks + 8 * l4 + j) * EDIM + l15];
                    _Float16 hh, hl;
                    f2h2(u, hh, hl);
                    vbh[j] = hh; vbl[j] = hl;
                }
#pragma unroll
                for (int mf2 = 0; mf2 < 2; ++mf2) {
                    const int aoff = (32 * w + 16 * mf2 + l15) * HSS + 32 * ks + 8 * l4;
                    const v8h vah = *(const v8h*)(hs_h + aoff);
                    const v8h val = *(const v8h*)(hs_l + aoff);
                    accL[mf2] = __builtin_amdgcn_mfma_f32_16x16x32_f16(vah, vbh, accL[mf2], 0, 0, 0);
                    accL[mf2] = __builtin_amdgcn_mfma_f32_16x16x32_f16(val, vbh, accL[mf2], 0, 0, 0);
                    accL[mf2] = __builtin_amdgcn_mfma_f32_16x16x32_f16(vah, vbl, accL[mf2], 0, 0, 0);
                }
            }
            if (h == 0) __syncthreads();   // half-1 GELU overwrites hs
        }
        // next fc pass's loop-top barrier protects hs before xs/ws overwrite
    }

    // ---- softmax + clip + top-2 + writes (R9/R18-proven mapping) ----
    float lg[8];
#pragma unroll
    for (int mf2 = 0; mf2 < 2; ++mf2)
#pragma unroll
        for (int r = 0; r < 4; ++r)
            lg[mf2 * 4 + r] = accL[mf2][r] + b2v;

    const int tx = l15;
#pragma unroll
    for (int i = 0; i < 8; ++i) {
        const int t = t0 + 32 * w + 16 * (i >> 2) + 4 * l4 + (i & 3);
        float mx = lg[i];
#pragma unroll
        for (int m = 1; m < 16; m <<= 1) mx = fmaxf(mx, __shfl_xor(mx, m, 64));
        float p = expf(lg[i] - mx);
        float s = p;
#pragma unroll
        for (int m = 1; m < 16; m <<= 1) s += __shfl_xor(s, m, 64);
        float pr = p / s;
        pr = fminf(fmaxf(pr, 1e-9f), 1.0f - 1e-9f);

        float v1 = pr; int i1 = tx;
#pragma unroll
        for (int m = 1; m < 16; m <<= 1) {
            const float vo = __shfl_xor(v1, m, 64);
            const int   io = __shfl_xor(i1, m, 64);
            if (vo > v1 || (vo == v1 && io < i1)) { v1 = vo; i1 = io; }
        }
        float v2 = (tx == i1) ? -1.0f : pr; int i2 = tx;
#pragma unroll
        for (int m = 1; m < 16; m <<= 1) {
            const float vo = __shfl_xor(v2, m, 64);
            const int   io = __shfl_xor(i2, m, 64);
            if (vo > v2 || (vo == v2 && io < i2)) { v2 = vo; i2 = io; }
        }
        const float rs = 1.0f / (v1 + v2);

        float* om  = out + (size_t)t * EDIM;
        float* orp = out + (size_t)NTOK * 18 + (size_t)t * EDIM;
        float* opf = out + (size_t)NTOK * 34 + (size_t)t * EDIM;
        om[tx]  = (tx == i1 || tx == i2) ? 1.0f : 0.0f;
        orp[tx] = (tx == i1) ? v1 * rs : ((tx == i2) ? v2 * rs : 0.0f);
        opf[tx] = pr;
        if (tx == 0) {
            float2* oi = (float2*)(out + (size_t)NTOK * 16 + (size_t)t * 2);
            *oi = make_float2((float)i1, (float)i2);
        }
    }
}

// ---------------- R15 fallback (verbatim), used if ws too small ----------------
#define XST  40
#define HST  68
#define FCHB 64
__global__ __launch_bounds__(256, 2)
void router_mfma7(const float* __restrict__ inp,
                  const float* __restrict__ cnd,
                  const float* __restrict__ W1,
                  const float* __restrict__ b1,
                  const float* __restrict__ W2,
                  const float* __restrict__ b2,
                  float* __restrict__ out)
{
    __shared__ __align__(16) char smem[34816];
    _Float16* xs_h = (_Float16*)(smem);
    _Float16* xs_l = (_Float16*)(smem + 10240);
    _Float16* ws_h = (_Float16*)(smem + 20480);
    _Float16* ws_l = (_Float16*)(smem + 25600);
    float*    hs   = (float*)(smem);

    const int tid  = threadIdx.x;
    const int lane = tid & 63;
    const int w    = tid >> 6;
    const int wr   = w >> 1;
    const int wc   = w & 1;
    const int l15  = lane & 15;
    const int l4   = lane >> 4;
    const int t0   = blockIdx.x * TBLK;
    const int ty   = tid >> 4;
    const int tx   = tid & 15;
    const int kq   = tid & 7;
    const int xr   = tid >> 3;
    const int fcl  = tid & 63;
    const int kg   = tid >> 6;

    float lg[8];
    { const float bb = b2[tx];
#pragma unroll
      for (int i = 0; i < 8; ++i) lg[i] = bb; }

    for (int fc = 0; fc < FDIM; fc += FCHB) {
        v4f acc[4][2];
#pragma unroll
        for (int mf = 0; mf < 4; ++mf)
#pragma unroll
            for (int nf = 0; nf < 2; ++nf) acc[mf][nf] = (v4f){0.f,0.f,0.f,0.f};

        for (int st = 0; st < 16; ++st) {
            const int kc = st * KST;
            __syncthreads();
            {
                const float* src = (kc < HDIM) ? (inp + (size_t)t0 * HDIM + kc)
                                               : (cnd + (size_t)t0 * HDIM + (kc - HDIM));
#pragma unroll
                for (int p = 0; p < 4; ++p) {
                    const int row = xr + 32 * p;
                    const float4 v = *(const float4*)(src + (size_t)row * HDIM + kq * 4);
                    _Float16 h0,l0,h1,l1,h2,l2,h3,l3;
                    f2h2(v.x,h0,l0); f2h2(v.y,h1,l1); f2h2(v.z,h2,l2); f2h2(v.w,h3,l3);
                    v4h hh, hl;
                    hh[0]=h0; hh[1]=h1; hh[2]=h2; hh[3]=h3;
                    hl[0]=l0; hl[1]=l1; hl[2]=l2; hl[3]=l3;
                    *(v4h*)(xs_h + row * XST + kq * 4) = hh;
                    *(v4h*)(xs_l + row * XST + kq * 4) = hl;
                }
            }
#pragma unroll
            for (int s = 0; s < 2; ++s) {
                const int kb = 4 * kg + 16 * s;
                const float u0 = W1[(size_t)(kc + kb + 0) * FDIM + fc + fcl];
                const float u1 = W1[(size_t)(kc + kb + 1) * FDIM + fc + fcl];
                const float u2 = W1[(size_t)(kc + kb + 2) * FDIM + fc + fcl];
                const float u3 = W1[(size_t)(kc + kb + 3) * FDIM + fc + fcl];
                _Float16 h0,l0,h1,l1,h2,l2,h3,l3;
                f2h2(u0,h0,l0); f2h2(u1,h1,l1); f2h2(u2,h2,l2); f2h2(u3,h3,l3);
                v4h hh, hl;
                hh[0]=h0; hh[1]=h1; hh[2]=h2; hh[3]=h3;
                hl[0]=l0; hl[1]=l1; hl[2]=l2; hl[3]=l3;
                *(v4h*)(ws_h + fcl * XST + kb) = hh;
                *(v4h*)(ws_l + fcl * XST + kb) = hl;
            }
            __syncthreads();
            {
                v8h bh[2], bl[2];
#pragma unroll
                for (int nf = 0; nf < 2; ++nf) {
                    const int off = (32 * wc + 16 * nf + l15) * XST + 8 * l4;
                    bh[nf] = *(const v8h*)(ws_h + off);
                    bl[nf] = *(const v8h*)(ws_l + off);
                }
#pragma unroll
                for (int mf = 0; mf < 4; ++mf) {
                    const int off = (64 * wr + 16 * mf + l15) * XST + 8 * l4;
                    const v8h ah = *(const v8h*)(xs_h + off);
                    const v8h al = *(const v8h*)(xs_l + off);
#pragma unroll
                    for (int nf = 0; nf < 2; ++nf) {
                        acc[mf][nf] = __builtin_amdgcn_mfma_f32_16x16x32_f16(ah, bh[nf], acc[mf][nf], 0, 0, 0);
                        acc[mf][nf] = __builtin_amdgcn_mfma_f32_16x16x32_f16(al, bh[nf], acc[mf][nf], 0, 0, 0);
                        acc[mf][nf] = __builtin_amdgcn_mfma_f32_16x16x32_f16(ah, bl[nf], acc[mf][nf], 0, 0, 0);
                    }
                }
            }
        }
        __syncthreads();
        {
            float b1v[2];
#pragma unroll
            for (int nf = 0; nf < 2; ++nf) b1v[nf] = b1[fc + 32 * wc + 16 * nf + l15];
#pragma unroll
            for (int mf = 0; mf < 4; ++mf)
#pragma unroll
                for (int nf = 0; nf < 2; ++nf)
#pragma unroll
                    for (int r = 0; r < 4; ++r) {
                        const float v = acc[mf][nf][r] + b1v[nf];
                        const int tok  = 64 * wr + 16 * mf + 4 * l4 + r;
                        const int fcol = 32 * wc + 16 * nf + l15;
                        hs[tok * HST + fcol] = 0.5f * v * (1.0f + erff(v * 0.70710678118654752f));
                    }
        }
        __syncthreads();
#pragma unroll
        for (int jb = 0; jb < 16; ++jb) {
            const int jbs = (jb + 4 * l4) & 15;
            float w2v[4];
#pragma unroll
            for (int j = 0; j < 4; ++j)
                w2v[j] = W2[(size_t)(fc + jbs * 4 + j) * EDIM + tx];
#pragma unroll
            for (int i = 0; i < 8; ++i) {
                const float4 hv = *(const float4*)(hs + (ty * 8 + i) * HST + jbs * 4);
                lg[i] = fmaf(hv.x, w2v[0], lg[i]);
                lg[i] = fmaf(hv.y, w2v[1], lg[i]);
                lg[i] = fmaf(hv.z, w2v[2], lg[i]);
                lg[i] = fmaf(hv.w, w2v[3], lg[i]);
            }
        }
    }
#pragma unroll
    for (int i = 0; i < 8; ++i) {
        const int t = t0 + ty * 8 + i;
        float mx = lg[i];
#pragma unroll
        for (int m = 1; m < 16; m <<= 1) mx = fmaxf(mx, __shfl_xor(mx, m, 64));
        float p = expf(lg[i] - mx);
        float s = p;
#pragma unroll
        for (int m = 1; m < 16; m <<= 1) s += __shfl_xor(s, m, 64);
        float pr = p / s;
        pr = fminf(fmaxf(pr, 1e-9f), 1.0f - 1e-9f);
        float v1 = pr; int i1 = tx;
#pragma unroll
        for (int m = 1; m < 16; m <<= 1) {
            const float vo = __shfl_xor(v1, m, 64);
            const int   io = __shfl_xor(i1, m, 64);
            if (vo > v1 || (vo == v1 && io < i1)) { v1 = vo; i1 = io; }
        }
        float v2 = (tx == i1) ? -1.0f : pr; int i2 = tx;
#pragma unroll
        for (int m = 1; m < 16; m <<= 1) {
            const float vo = __shfl_xor(v2, m, 64);
            const int   io = __shfl_xor(i2, m, 64);
            if (vo > v2 || (vo == v2 && io < i2)) { v2 = vo; i2 = io; }
        }
        const float rs = 1.0f / (v1 + v2);
        float* om  = out + (size_t)t * EDIM;
        float* orp = out + (size_t)NTOK * 18 + (size_t)t * EDIM;
        float* opf = out + (size_t)NTOK * 34 + (size_t)t * EDIM;
        om[tx]  = (tx == i1 || tx == i2) ? 1.0f : 0.0f;
        orp[tx] = (tx == i1) ? v1 * rs : ((tx == i2) ? v2 * rs : 0.0f);
        opf[tx] = pr;
        if (tx == 0) {
            float2* oi = (float2*)(out + (size_t)NTOK * 16 + (size_t)t * 2);
            *oi = make_float2((float)i1, (float)i2);
        }
    }
}

extern "C" void kernel_launch(void* const* d_in, const int* in_sizes, int n_in,
                              void* d_out, int out_size, void* d_ws, size_t ws_size,
                              hipStream_t stream)
{
    const float* inp = (const float*)d_in[0];
    const float* cnd = (const float*)d_in[1];
    const float* W1  = (const float*)d_in[2];
    const float* b1  = (const float*)d_in[3];
    const float* W2  = (const float*)d_in[4];
    const float* b2  = (const float*)d_in[5];
    float* out = (float*)d_out;

    if (ws_size >= WS_NEED) {
        char* wsb = (char*)d_ws;
        _Float16* xh  = (_Float16*)(wsb);
        _Float16* xl  = (_Float16*)(wsb + WS_XL);
        _Float16* w1h = (_Float16*)(wsb + WS_W1H);
        _Float16* w1l = (_Float16*)(wsb + WS_W1L);
        hipLaunchKernelGGL(prep_x, dim3(32768), dim3(256), 0, stream, inp, cnd, xh, xl);
        hipLaunchKernelGGL(prep_w1, dim3(256), dim3(256), 0, stream, W1, w1h, w1l);
        hipLaunchKernelGGL(router_mfma11, dim3(NTOK / TBLK), dim3(256), 0, stream,
                           xh, xl, w1h, w1l, b1, W2, b2, out);
    } else {
        hipLaunchKernelGGL(router_mfma7, dim3(NTOK / TBLK), dim3(256), 0, stream,
                           inp, cnd, W1, b1, W2, b2, out);
    }
}

// Round 20
// 652.836 us; speedup vs baseline: 2.7526x; 1.0540x over previous
//
#include <hip/hip_runtime.h>
#include <math.h>

#define NTOK 131072
#define HDIM 256
#define DDIM 512
#define FDIM 1024
#define EDIM 16
#define TBLK 128
#define FCH  128
#define KST  32
#define HSS  68    // hs f16 row stride (136 B)

// d_ws layout (bytes): xh frag-tiles @0 (134217728), xl @134217728,
// w1h frags @268435456 (1048576), w1l @269484032 (1048576) -> 270532608
#define WS_XL   134217728ULL
#define WS_W1H  268435456ULL
#define WS_W1L  269484032ULL
#define WS_NEED 270532608ULL

typedef __attribute__((ext_vector_type(8))) _Float16 v8h;
typedef __attribute__((ext_vector_type(4))) _Float16 v4h;
typedef __attribute__((ext_vector_type(4))) float v4f;

__device__ __forceinline__ void f2h2(float v, _Float16& h, _Float16& l) {
    h = (_Float16)v;
    l = (_Float16)(v - (float)h);
}

__device__ __forceinline__ void pack8(const float* u, v8h& hh, v8h& hl) {
    _Float16 h0,l0,h1,l1,h2,l2,h3,l3,h4,l4,h5,l5,h6,l6,h7,l7;
    f2h2(u[0],h0,l0); f2h2(u[1],h1,l1); f2h2(u[2],h2,l2); f2h2(u[3],h3,l3);
    f2h2(u[4],h4,l4); f2h2(u[5],h5,l5); f2h2(u[6],h6,l6); f2h2(u[7],h7,l7);
    hh[0]=h0; hh[1]=h1; hh[2]=h2; hh[3]=h3; hh[4]=h4; hh[5]=h5; hh[6]=h6; hh[7]=h7;
    hl[0]=l0; hl[1]=l1; hl[2]=l2; hl[3]=l3; hl[4]=l4; hl[5]=l5; hl[6]=l6; hl[7]=l7;
}

// async global->LDS, 16B per lane; LDS dest must be wave-uniform base + lane*16
// (our layouts are exactly linear per wave). Compiler inserts vmcnt(0) at barriers.
__device__ __forceinline__ void gl16(const void* g, void* l) {
    __builtin_amdgcn_global_load_lds(
        (const __attribute__((address_space(1))) void*)g,
        (__attribute__((address_space(3))) void*)l, 16, 0, 0);
}

// x -> f16 hi/lo, MFMA-A-fragment tile order (tile T=(tb,st): [frag][lane][8])
__global__ __launch_bounds__(256, 4)
void prep_x(const float* __restrict__ inp, const float* __restrict__ cnd,
            _Float16* __restrict__ xh, _Float16* __restrict__ xl)
{
    const size_t g = (size_t)blockIdx.x * 256 + threadIdx.x;
    const int lane = (int)(g & 63);
    const int fg   = (int)((g >> 6) & 7);
    const int T    = (int)(g >> 9);
    const int tb = T >> 4, st = T & 15;
    const int tok = tb * TBLK + fg * 16 + (lane & 15);
    const int k   = st * KST + (lane >> 4) * 8;
    const float* src = (k < HDIM) ? (inp + (size_t)tok * HDIM + k)
                                  : (cnd + (size_t)tok * HDIM + (k - HDIM));
    float u[8];
    *(float4*)&u[0] = *(const float4*)(src);
    *(float4*)&u[4] = *(const float4*)(src + 4);
    v8h hh, hl;
    pack8(u, hh, hl);
    *(v8h*)(xh + g * 8) = hh;
    *(v8h*)(xl + g * 8) = hl;
}

// W1 -> f16 hi/lo, MFMA-B-fragment order
__global__ __launch_bounds__(256, 4)
void prep_w1(const float* __restrict__ W1,
             _Float16* __restrict__ wh, _Float16* __restrict__ wl)
{
    const int g = blockIdx.x * 256 + threadIdx.x;
    const int lane = g & 63;
    const int K = (g >> 6) & 15;
    const int F = g >> 10;
    const int f  = F * 16 + (lane & 15);
    const int kb = K * KST + (lane >> 4) * 8;
    float u[8];
#pragma unroll
    for (int e = 0; e < 8; ++e)
        u[e] = W1[(size_t)(kb + e) * FDIM + f];
    v8h hh, hl;
    pack8(u, hh, hl);
    *(v8h*)(wh + (size_t)g * 8) = hh;
    *(v8h*)(wl + (size_t)g * 8) = hl;
}

// Main: R19 + (a) global_load_lds staging (no VGPR round-trip / ds_write),
// (b) A-resident MFMA loop: 8 A-reads + 8 B-reads per st (was 24 reads).
// LDS 34816: xs_h @0 (8192), xs_l @8192, ws_h @16384 (8192), ws_l @24576;
// GEMM2 phase alias: hs_h @0 (17408), hs_l @17408.
__global__ __launch_bounds__(256, 2)
void router_mfma12(const _Float16* __restrict__ xh, const _Float16* __restrict__ xl,
                   const _Float16* __restrict__ w1h, const _Float16* __restrict__ w1l,
                   const float* __restrict__ b1,
                   const float* __restrict__ W2,
                   const float* __restrict__ b2,
                   float* __restrict__ out)
{
    __shared__ __align__(16) char smem[34816];
    _Float16* xs_h = (_Float16*)(smem);
    _Float16* xs_l = (_Float16*)(smem + 8192);
    _Float16* ws_h = (_Float16*)(smem + 16384);
    _Float16* ws_l = (_Float16*)(smem + 24576);
    _Float16* hs_h = (_Float16*)(smem);            // alias, barrier-separated
    _Float16* hs_l = (_Float16*)(smem + 17408);

    const int tid  = threadIdx.x;
    const int lane = tid & 63;
    const int w    = tid >> 6;        // wave 0..3
    const int wr   = w >> 1;          // token half (64)
    const int wf   = w & 1;           // F half (64 of the 128-chunk)
    const int l15  = lane & 15;
    const int l4   = lane >> 4;
    const int t0   = blockIdx.x * TBLK;

    const float b2v = b2[l15];
    v4f accL[2] = {{0.f,0.f,0.f,0.f},{0.f,0.f,0.f,0.f}};

    for (int fc = 0; fc < FDIM; fc += FCH) {
        v4f acc[4][4];
#pragma unroll
        for (int mf = 0; mf < 4; ++mf)
#pragma unroll
            for (int nf = 0; nf < 4; ++nf)
                acc[mf][nf] = (v4f){0.f,0.f,0.f,0.f};

        for (int st = 0; st < 16; ++st) {
            __syncthreads();   // prior MFMA xs/ws reads or GEMM2 hs reads done
            // ---- stage x + W1 tiles: async global->LDS, 16B lanes, linear ----
            {
                const char* sh = (const char*)(xh + ((size_t)blockIdx.x * 16 + st) * 4096);
                const char* sl = (const char*)(xl + ((size_t)blockIdx.x * 16 + st) * 4096);
                gl16(sh + tid * 16,        smem + tid * 16);                  // xs_h lo-half
                gl16(sh + tid * 16 + 4096, smem + tid * 16 + 4096);           // xs_h hi-half
                gl16(sl + tid * 16,        smem + 8192 + tid * 16);           // xs_l
                gl16(sl + tid * 16 + 4096, smem + 8192 + tid * 16 + 4096);
                const size_t wb0 = (((size_t)((fc >> 4) + (tid >> 6)) * 16 + st) * 64
                                    + (tid & 63)) * 16;
                const size_t wb1 = (((size_t)((fc >> 4) + 4 + (tid >> 6)) * 16 + st) * 64
                                    + (tid & 63)) * 16;
                gl16((const char*)w1h + wb0, smem + 16384 + tid * 16);        // ws_h f0..3
                gl16((const char*)w1h + wb1, smem + 16384 + tid * 16 + 4096); // ws_h f4..7
                gl16((const char*)w1l + wb0, smem + 24576 + tid * 16);        // ws_l
                gl16((const char*)w1l + wb1, smem + 24576 + tid * 16 + 4096);
            }
            __syncthreads();   // compiler emits vmcnt(0) before this barrier
            // ---- MFMA 16x16x32 f16: all 8 A-frags resident, B streamed ----
            {
                v8h ah[4], al[4];
#pragma unroll
                for (int mf = 0; mf < 4; ++mf) {
                    const int aoff = ((4 * wr + mf) * 64 + lane) * 8;
                    ah[mf] = *(const v8h*)(xs_h + aoff);
                    al[mf] = *(const v8h*)(xs_l + aoff);
                }
#pragma unroll
                for (int nf = 0; nf < 4; ++nf) {
                    const int boff = ((4 * wf + nf) * 64 + lane) * 8;
                    const v8h bh = *(const v8h*)(ws_h + boff);
                    const v8h bl = *(const v8h*)(ws_l + boff);
#pragma unroll
                    for (int mf = 0; mf < 4; ++mf) {
                        acc[mf][nf] = __builtin_amdgcn_mfma_f32_16x16x32_f16(ah[mf], bh, acc[mf][nf], 0, 0, 0);
                        acc[mf][nf] = __builtin_amdgcn_mfma_f32_16x16x32_f16(al[mf], bh, acc[mf][nf], 0, 0, 0);
                        acc[mf][nf] = __builtin_amdgcn_mfma_f32_16x16x32_f16(ah[mf], bl, acc[mf][nf], 0, 0, 0);
                    }
                }
            }
        }
        __syncthreads();   // all MFMA xs/ws reads done; hs may alias

        float b1v[4];
#pragma unroll
        for (int nf = 0; nf < 4; ++nf)
            b1v[nf] = b1[fc + 64 * wf + 16 * nf + l15];

#pragma unroll
        for (int h = 0; h < 2; ++h) {
            // ---- GELU: waves with wf==h write their 64 F cols (local 0..63) ----
            if (wf == h) {
#pragma unroll
                for (int mf = 0; mf < 4; ++mf)
#pragma unroll
                    for (int nf = 0; nf < 4; ++nf)
#pragma unroll
                        for (int r = 0; r < 4; ++r) {
                            const float v = acc[mf][nf][r] + b1v[nf];
                            const float gl = 0.5f * v * (1.0f + erff(v * 0.70710678118654752f));
                            _Float16 hh, hl;
                            f2h2(gl, hh, hl);
                            const int tok  = 64 * wr + 16 * mf + 4 * l4 + r;
                            const int fcol = 16 * nf + l15;   // local 0..63
                            hs_h[tok * HSS + fcol] = hh;
                            hs_l[tok * HSS + fcol] = hl;
                        }
            }
            __syncthreads();
            // ---- GEMM2 half h: MFMA, K=64 (R9/R18-validated scheme) ----
#pragma unroll
            for (int ks = 0; ks < 2; ++ks) {
                v8h vbh, vbl;
#pragma unroll
                for (int j = 0; j < 8; ++j) {
                    const float u = W2[(size_t)(fc + 64 * h + 32 * ks + 8 * l4 + j) * EDIM + l15];
                    _Float16 hh, hl;
                    f2h2(u, hh, hl);
                    vbh[j] = hh; vbl[j] = hl;
                }
#pragma unroll
                for (int mf2 = 0; mf2 < 2; ++mf2) {
                    const int aoff = (32 * w + 16 * mf2 + l15) * HSS + 32 * ks + 8 * l4;
                    const v8h vah = *(const v8h*)(hs_h + aoff);
                    const v8h val = *(const v8h*)(hs_l + aoff);
                    accL[mf2] = __builtin_amdgcn_mfma_f32_16x16x32_f16(vah, vbh, accL[mf2], 0, 0, 0);
                    accL[mf2] = __builtin_amdgcn_mfma_f32_16x16x32_f16(val, vbh, accL[mf2], 0, 0, 0);
                    accL[mf2] = __builtin_amdgcn_mfma_f32_16x16x32_f16(vah, vbl, accL[mf2], 0, 0, 0);
                }
            }
            if (h == 0) __syncthreads();   // half-1 GELU overwrites hs
        }
        // next fc pass's loop-top barrier protects hs before xs/ws overwrite
    }

    // ---- softmax + clip + top-2 + writes (R9/R18-proven mapping) ----
    float lg[8];
#pragma unroll
    for (int mf2 = 0; mf2 < 2; ++mf2)
#pragma unroll
        for (int r = 0; r < 4; ++r)
            lg[mf2 * 4 + r] = accL[mf2][r] + b2v;

    const int tx = l15;
#pragma unroll
    for (int i = 0; i < 8; ++i) {
        const int t = t0 + 32 * w + 16 * (i >> 2) + 4 * l4 + (i & 3);
        float mx = lg[i];
#pragma unroll
        for (int m = 1; m < 16; m <<= 1) mx = fmaxf(mx, __shfl_xor(mx, m, 64));
        float p = expf(lg[i] - mx);
        float s = p;
#pragma unroll
        for (int m = 1; m < 16; m <<= 1) s += __shfl_xor(s, m, 64);
        float pr = p / s;
        pr = fminf(fmaxf(pr, 1e-9f), 1.0f - 1e-9f);

        float v1 = pr; int i1 = tx;
#pragma unroll
        for (int m = 1; m < 16; m <<= 1) {
            const float vo = __shfl_xor(v1, m, 64);
            const int   io = __shfl_xor(i1, m, 64);
            if (vo > v1 || (vo == v1 && io < i1)) { v1 = vo; i1 = io; }
        }
        float v2 = (tx == i1) ? -1.0f : pr; int i2 = tx;
#pragma unroll
        for (int m = 1; m < 16; m <<= 1) {
            const float vo = __shfl_xor(v2, m, 64);
            const int   io = __shfl_xor(i2, m, 64);
            if (vo > v2 || (vo == v2 && io < i2)) { v2 = vo; i2 = io; }
        }
        const float rs = 1.0f / (v1 + v2);

        float* om  = out + (size_t)t * EDIM;
        float* orp = out + (size_t)NTOK * 18 + (size_t)t * EDIM;
        float* opf = out + (size_t)NTOK * 34 + (size_t)t * EDIM;
        om[tx]  = (tx == i1 || tx == i2) ? 1.0f : 0.0f;
        orp[tx] = (tx == i1) ? v1 * rs : ((tx == i2) ? v2 * rs : 0.0f);
        opf[tx] = pr;
        if (tx == 0) {
            float2* oi = (float2*)(out + (size_t)NTOK * 16 + (size_t)t * 2);
            *oi = make_float2((float)i1, (float)i2);
        }
    }
}

// ---------------- R15 fallback (verbatim), used if ws too small ----------------
#define XST  40
#define HST  68
#define FCHB 64
__global__ __launch_bounds__(256, 2)
void router_mfma7(const float* __restrict__ inp,
                  const float* __restrict__ cnd,
                  const float* __restrict__ W1,
                  const float* __restrict__ b1,
                  const float* __restrict__ W2,
                  const float* __restrict__ b2,
                  float* __restrict__ out)
{
    __shared__ __align__(16) char smem[34816];
    _Float16* xs_h = (_Float16*)(smem);
    _Float16* xs_l = (_Float16*)(smem + 10240);
    _Float16* ws_h = (_Float16*)(smem + 20480);
    _Float16* ws_l = (_Float16*)(smem + 25600);
    float*    hs   = (float*)(smem);

    const int tid  = threadIdx.x;
    const int lane = tid & 63;
    const int w    = tid >> 6;
    const int wr   = w >> 1;
    const int wc   = w & 1;
    const int l15  = lane & 15;
    const int l4   = lane >> 4;
    const int t0   = blockIdx.x * TBLK;
    const int ty   = tid >> 4;
    const int tx   = tid & 15;
    const int kq   = tid & 7;
    const int xr   = tid >> 3;
    const int fcl  = tid & 63;
    const int kg   = tid >> 6;

    float lg[8];
    { const float bb = b2[tx];
#pragma unroll
      for (int i = 0; i < 8; ++i) lg[i] = bb; }

    for (int fc = 0; fc < FDIM; fc += FCHB) {
        v4f acc[4][2];
#pragma unroll
        for (int mf = 0; mf < 4; ++mf)
#pragma unroll
            for (int nf = 0; nf < 2; ++nf) acc[mf][nf] = (v4f){0.f,0.f,0.f,0.f};

        for (int st = 0; st < 16; ++st) {
            const int kc = st * KST;
            __syncthreads();
            {
                const float* src = (kc < HDIM) ? (inp + (size_t)t0 * HDIM + kc)
                                               : (cnd + (size_t)t0 * HDIM + (kc - HDIM));
#pragma unroll
                for (int p = 0; p < 4; ++p) {
                    const int row = xr + 32 * p;
                    const float4 v = *(const float4*)(src + (size_t)row * HDIM + kq * 4);
                    _Float16 h0,l0,h1,l1,h2,l2,h3,l3;
                    f2h2(v.x,h0,l0); f2h2(v.y,h1,l1); f2h2(v.z,h2,l2); f2h2(v.w,h3,l3);
                    v4h hh, hl;
                    hh[0]=h0; hh[1]=h1; hh[2]=h2; hh[3]=h3;
                    hl[0]=l0; hl[1]=l1; hl[2]=l2; hl[3]=l3;
                    *(v4h*)(xs_h + row * XST + kq * 4) = hh;
                    *(v4h*)(xs_l + row * XST + kq * 4) = hl;
                }
            }
#pragma unroll
            for (int s = 0; s < 2; ++s) {
                const int kb = 4 * kg + 16 * s;
                const float u0 = W1[(size_t)(kc + kb + 0) * FDIM + fc + fcl];
                const float u1 = W1[(size_t)(kc + kb + 1) * FDIM + fc + fcl];
                const float u2 = W1[(size_t)(kc + kb + 2) * FDIM + fc + fcl];
                const float u3 = W1[(size_t)(kc + kb + 3) * FDIM + fc + fcl];
                _Float16 h0,l0,h1,l1,h2,l2,h3,l3;
                f2h2(u0,h0,l0); f2h2(u1,h1,l1); f2h2(u2,h2,l2); f2h2(u3,h3,l3);
                v4h hh, hl;
                hh[0]=h0; hh[1]=h1; hh[2]=h2; hh[3]=h3;
                hl[0]=l0; hl[1]=l1; hl[2]=l2; hl[3]=l3;
                *(v4h*)(ws_h + fcl * XST + kb) = hh;
                *(v4h*)(ws_l + fcl * XST + kb) = hl;
            }
            __syncthreads();
            {
                v8h bh[2], bl[2];
#pragma unroll
                for (int nf = 0; nf < 2; ++nf) {
                    const int off = (32 * wc + 16 * nf + l15) * XST + 8 * l4;
                    bh[nf] = *(const v8h*)(ws_h + off);
                    bl[nf] = *(const v8h*)(ws_l + off);
                }
#pragma unroll
                for (int mf = 0; mf < 4; ++mf) {
                    const int off = (64 * wr + 16 * mf + l15) * XST + 8 * l4;
                    const v8h ah = *(const v8h*)(xs_h + off);
                    const v8h al = *(const v8h*)(xs_l + off);
#pragma unroll
                    for (int nf = 0; nf < 2; ++nf) {
                        acc[mf][nf] = __builtin_amdgcn_mfma_f32_16x16x32_f16(ah, bh[nf], acc[mf][nf], 0, 0, 0);
                        acc[mf][nf] = __builtin_amdgcn_mfma_f32_16x16x32_f16(al, bh[nf], acc[mf][nf], 0, 0, 0);
                        acc[mf][nf] = __builtin_amdgcn_mfma_f32_16x16x32_f16(ah, bl[nf], acc[mf][nf], 0, 0, 0);
                    }
                }
            }
        }
        __syncthreads();
        {
            float b1v[2];
#pragma unroll
            for (int nf = 0; nf < 2; ++nf) b1v[nf] = b1[fc + 32 * wc + 16 * nf + l15];
#pragma unroll
            for (int mf = 0; mf < 4; ++mf)
#pragma unroll
                for (int nf = 0; nf < 2; ++nf)
#pragma unroll
                    for (int r = 0; r < 4; ++r) {
                        const float v = acc[mf][nf][r] + b1v[nf];
                        const int tok  = 64 * wr + 16 * mf + 4 * l4 + r;
                        const int fcol = 32 * wc + 16 * nf + l15;
                        hs[tok * HST + fcol] = 0.5f * v * (1.0f + erff(v * 0.70710678118654752f));
                    }
        }
        __syncthreads();
#pragma unroll
        for (int jb = 0; jb < 16; ++jb) {
            const int jbs = (jb + 4 * l4) & 15;
            float w2v[4];
#pragma unroll
            for (int j = 0; j < 4; ++j)
                w2v[j] = W2[(size_t)(fc + jbs * 4 + j) * EDIM + tx];
#pragma unroll
            for (int i = 0; i < 8; ++i) {
                const float4 hv = *(const float4*)(hs + (ty * 8 + i) * HST + jbs * 4);
                lg[i] = fmaf(hv.x, w2v[0], lg[i]);
                lg[i] = fmaf(hv.y, w2v[1], lg[i]);
                lg[i] = fmaf(hv.z, w2v[2], lg[i]);
                lg[i] = fmaf(hv.w, w2v[3], lg[i]);
            }
        }
    }
#pragma unroll
    for (int i = 0; i < 8; ++i) {
        const int t = t0 + ty * 8 + i;
        float mx = lg[i];
#pragma unroll
        for (int m = 1; m < 16; m <<= 1) mx = fmaxf(mx, __shfl_xor(mx, m, 64));
        float p = expf(lg[i] - mx);
        float s = p;
#pragma unroll
        for (int m = 1; m < 16; m <<= 1) s += __shfl_xor(s, m, 64);
        float pr = p / s;
        pr = fminf(fmaxf(pr, 1e-9f), 1.0f - 1e-9f);
        float v1 = pr; int i1 = tx;
#pragma unroll
        for (int m = 1; m < 16; m <<= 1) {
            const float vo = __shfl_xor(v1, m, 64);
            const int   io = __shfl_xor(i1, m, 64);
            if (vo > v1 || (vo == v1 && io < i1)) { v1 = vo; i1 = io; }
        }
        float v2 = (tx == i1) ? -1.0f : pr; int i2 = tx;
#pragma unroll
        for (int m = 1; m < 16; m <<= 1) {
            const float vo = __shfl_xor(v2, m, 64);
            const int   io = __shfl_xor(i2, m, 64);
            if (vo > v2 || (vo == v2 && io < i2)) { v2 = vo; i2 = io; }
        }
        const float rs = 1.0f / (v1 + v2);
        float* om  = out + (size_t)t * EDIM;
        float* orp = out + (size_t)NTOK * 18 + (size_t)t * EDIM;
        float* opf = out + (size_t)NTOK * 34 + (size_t)t * EDIM;
        om[tx]  = (tx == i1 || tx == i2) ? 1.0f : 0.0f;
        orp[tx] = (tx == i1) ? v1 * rs : ((tx == i2) ? v2 * rs : 0.0f);
        opf[tx] = pr;
        if (tx == 0) {
            float2* oi = (float2*)(out + (size_t)NTOK * 16 + (size_t)t * 2);
            *oi = make_float2((float)i1, (float)i2);
        }
    }
}

extern "C" void kernel_launch(void* const* d_in, const int* in_sizes, int n_in,
                              void* d_out, int out_size, void* d_ws, size_t ws_size,
                              hipStream_t stream)
{
    const float* inp = (const float*)d_in[0];
    const float* cnd = (const float*)d_in[1];
    const float* W1  = (const float*)d_in[2];
    const float* b1  = (const float*)d_in[3];
    const float* W2  = (const float*)d_in[4];
    const float* b2  = (const float*)d_in[5];
    float* out = (float*)d_out;

    if (ws_size >= WS_NEED) {
        char* wsb = (char*)d_ws;
        _Float16* xh  = (_Float16*)(wsb);
        _Float16* xl  = (_Float16*)(wsb + WS_XL);
        _Float16* w1h = (_Float16*)(wsb + WS_W1H);
        _Float16* w1l = (_Float16*)(wsb + WS_W1L);
        hipLaunchKernelGGL(prep_x, dim3(32768), dim3(256), 0, stream, inp, cnd, xh, xl);
        hipLaunchKernelGGL(prep_w1, dim3(256), dim3(256), 0, stream, W1, w1h, w1l);
        hipLaunchKernelGGL(router_mfma12, dim3(NTOK / TBLK), dim3(256), 0, stream,
                           xh, xl, w1h, w1l, b1, W2, b2, out);
    } else {
        hipLaunchKernelGGL(router_mfma7, dim3(NTOK / TBLK), dim3(256), 0, stream,
                           inp, cnd, W1, b1, W2, b2, out);
    }
}

// Round 21
// 632.700 us; speedup vs baseline: 2.8402x; 1.0318x over previous
//
#include <hip/hip_runtime.h>
#include <math.h>

#define NTOK 131072
#define HDIM 256
#define DDIM 512
#define FDIM 1024
#define EDIM 16
#define TBLK 128
#define FCH  128
#define KST  32
#define HSS  68    // hs f16 row stride (136 B)

// d_ws layout (bytes): xh frag-tiles @0 (134217728), xl @134217728,
// w1h frags @268435456 (1048576), w1l @269484032 (1048576) -> 270532608
#define WS_XL   134217728ULL
#define WS_W1H  268435456ULL
#define WS_W1L  269484032ULL
#define WS_NEED 270532608ULL

typedef __attribute__((ext_vector_type(8))) _Float16 v8h;
typedef __attribute__((ext_vector_type(4))) _Float16 v4h;
typedef __attribute__((ext_vector_type(4))) float v4f;

__device__ __forceinline__ void f2h2(float v, _Float16& h, _Float16& l) {
    h = (_Float16)v;
    l = (_Float16)(v - (float)h);
}

__device__ __forceinline__ void pack8(const float* u, v8h& hh, v8h& hl) {
    _Float16 h0,l0,h1,l1,h2,l2,h3,l3,h4,l4,h5,l5,h6,l6,h7,l7;
    f2h2(u[0],h0,l0); f2h2(u[1],h1,l1); f2h2(u[2],h2,l2); f2h2(u[3],h3,l3);
    f2h2(u[4],h4,l4); f2h2(u[5],h5,l5); f2h2(u[6],h6,l6); f2h2(u[7],h7,l7);
    hh[0]=h0; hh[1]=h1; hh[2]=h2; hh[3]=h3; hh[4]=h4; hh[5]=h5; hh[6]=h6; hh[7]=h7;
    hl[0]=l0; hl[1]=l1; hl[2]=l2; hl[3]=l3; hl[4]=l4; hl[5]=l5; hl[6]=l6; hl[7]=l7;
}

// async global->LDS, 16B per lane (linear dest = wave-uniform base + lane*16)
__device__ __forceinline__ void gl16(const void* g, void* l) {
    __builtin_amdgcn_global_load_lds(
        (const __attribute__((address_space(1))) void*)g,
        (__attribute__((address_space(3))) void*)l, 16, 0, 0);
}

// x -> f16 hi/lo, MFMA-A-fragment tile order (tile T=(tb,st): [frag][lane][8])
__global__ __launch_bounds__(256, 4)
void prep_x(const float* __restrict__ inp, const float* __restrict__ cnd,
            _Float16* __restrict__ xh, _Float16* __restrict__ xl)
{
    const size_t g = (size_t)blockIdx.x * 256 + threadIdx.x;
    const int lane = (int)(g & 63);
    const int fg   = (int)((g >> 6) & 7);
    const int T    = (int)(g >> 9);
    const int tb = T >> 4, st = T & 15;
    const int tok = tb * TBLK + fg * 16 + (lane & 15);
    const int k   = st * KST + (lane >> 4) * 8;
    const float* src = (k < HDIM) ? (inp + (size_t)tok * HDIM + k)
                                  : (cnd + (size_t)tok * HDIM + (k - HDIM));
    float u[8];
    *(float4*)&u[0] = *(const float4*)(src);
    *(float4*)&u[4] = *(const float4*)(src + 4);
    v8h hh, hl;
    pack8(u, hh, hl);
    *(v8h*)(xh + g * 8) = hh;
    *(v8h*)(xl + g * 8) = hl;
}

// W1 -> f16 hi/lo, MFMA-B-fragment order
__global__ __launch_bounds__(256, 4)
void prep_w1(const float* __restrict__ W1,
             _Float16* __restrict__ wh, _Float16* __restrict__ wl)
{
    const int g = blockIdx.x * 256 + threadIdx.x;
    const int lane = g & 63;
    const int K = (g >> 6) & 15;
    const int F = g >> 10;
    const int f  = F * 16 + (lane & 15);
    const int kb = K * KST + (lane >> 4) * 8;
    float u[8];
#pragma unroll
    for (int e = 0; e < 8; ++e)
        u[e] = W1[(size_t)(kb + e) * FDIM + f];
    v8h hh, hl;
    pack8(u, hh, hl);
    *(v8h*)(wh + (size_t)g * 8) = hh;
    *(v8h*)(wl + (size_t)g * 8) = hl;
}

// stage one (x, W1) tile pair into LDS buffer b (pure async copies)
__device__ __forceinline__ void stage_tiles(char* smem, int b, int tid,
        const _Float16* xh, const _Float16* xl,
        const _Float16* w1h, const _Float16* w1l,
        int blk, int fc, int st)
{
    char* base = smem + b * 32768;
    const char* sh = (const char*)(xh + ((size_t)blk * 16 + st) * 4096);
    const char* sl = (const char*)(xl + ((size_t)blk * 16 + st) * 4096);
    gl16(sh + tid * 16,        base + tid * 16);
    gl16(sh + tid * 16 + 4096, base + tid * 16 + 4096);
    gl16(sl + tid * 16,        base + 8192 + tid * 16);
    gl16(sl + tid * 16 + 4096, base + 8192 + tid * 16 + 4096);
    const size_t wb0 = (((size_t)((fc >> 4) + (tid >> 6)) * 16 + st) * 64
                        + (tid & 63)) * 16;
    const size_t wb1 = (((size_t)((fc >> 4) + 4 + (tid >> 6)) * 16 + st) * 64
                        + (tid & 63)) * 16;
    gl16((const char*)w1h + wb0, base + 16384 + tid * 16);
    gl16((const char*)w1h + wb1, base + 16384 + tid * 16 + 4096);
    gl16((const char*)w1l + wb0, base + 24576 + tid * 16);
    gl16((const char*)w1l + wb1, base + 24576 + tid * 16 + 4096);
}

// Main: R20 + double-buffered LDS with prefetch-before-MFMA (T3-minimum):
// per st: STAGE(st+1 -> buf^1); MFMA(buf); barrier. The barrier's vmcnt(0)
// drain now lands AFTER ~240 cyc of MFMA cover instead of right after issue.
// LDS 65536: buf[2] x {xs_h,xs_l,ws_h,ws_l} @ b*32768; GEMM2 phase alias:
// hs_h @0 (17408), hs_l @17408.
__global__ __launch_bounds__(256, 2)
void router_mfma13(const _Float16* __restrict__ xh, const _Float16* __restrict__ xl,
                   const _Float16* __restrict__ w1h, const _Float16* __restrict__ w1l,
                   const float* __restrict__ b1,
                   const float* __restrict__ W2,
                   const float* __restrict__ b2,
                   float* __restrict__ out)
{
    __shared__ __align__(16) char smem[65536];
    _Float16* hs_h = (_Float16*)(smem);            // alias, barrier-separated
    _Float16* hs_l = (_Float16*)(smem + 17408);

    const int tid  = threadIdx.x;
    const int lane = tid & 63;
    const int w    = tid >> 6;        // wave 0..3
    const int wr   = w >> 1;          // token half (64)
    const int wf   = w & 1;           // F half (64 of the 128-chunk)
    const int l15  = lane & 15;
    const int l4   = lane >> 4;
    const int t0   = blockIdx.x * TBLK;

    const float b2v = b2[l15];
    v4f accL[2] = {{0.f,0.f,0.f,0.f},{0.f,0.f,0.f,0.f}};

    int cur = 0;
    for (int fc = 0; fc < FDIM; fc += FCH) {
        v4f acc[4][4];
#pragma unroll
        for (int mf = 0; mf < 4; ++mf)
#pragma unroll
            for (int nf = 0; nf < 4; ++nf)
                acc[mf][nf] = (v4f){0.f,0.f,0.f,0.f};

        __syncthreads();   // prior GEMM2 hs reads (fc>0) / init done
        stage_tiles(smem, cur, tid, xh, xl, w1h, w1l, blockIdx.x, fc, 0);
        __syncthreads();   // vmcnt(0): st=0 tiles resident

        for (int st = 0; st < 16; ++st) {
            // ---- prefetch next tile into the other buffer (issues only) ----
            if (st < 15)
                stage_tiles(smem, cur ^ 1, tid, xh, xl, w1h, w1l,
                            blockIdx.x, fc, st + 1);
            // ---- MFMA 16x16x32 f16 on buf[cur]: A resident, B streamed ----
            {
                const _Float16* xs_h = (const _Float16*)(smem + cur * 32768);
                const _Float16* xs_l = (const _Float16*)(smem + cur * 32768 + 8192);
                const _Float16* ws_h = (const _Float16*)(smem + cur * 32768 + 16384);
                const _Float16* ws_l = (const _Float16*)(smem + cur * 32768 + 24576);
                v8h ah[4], al[4];
#pragma unroll
                for (int mf = 0; mf < 4; ++mf) {
                    const int aoff = ((4 * wr + mf) * 64 + lane) * 8;
                    ah[mf] = *(const v8h*)(xs_h + aoff);
                    al[mf] = *(const v8h*)(xs_l + aoff);
                }
#pragma unroll
                for (int nf = 0; nf < 4; ++nf) {
                    const int boff = ((4 * wf + nf) * 64 + lane) * 8;
                    const v8h bh = *(const v8h*)(ws_h + boff);
                    const v8h bl = *(const v8h*)(ws_l + boff);
#pragma unroll
                    for (int mf = 0; mf < 4; ++mf) {
                        acc[mf][nf] = __builtin_amdgcn_mfma_f32_16x16x32_f16(ah[mf], bh, acc[mf][nf], 0, 0, 0);
                        acc[mf][nf] = __builtin_amdgcn_mfma_f32_16x16x32_f16(al[mf], bh, acc[mf][nf], 0, 0, 0);
                        acc[mf][nf] = __builtin_amdgcn_mfma_f32_16x16x32_f16(ah[mf], bl, acc[mf][nf], 0, 0, 0);
                    }
                }
            }
            __syncthreads();   // drains prefetch; buf[cur] reads complete
            cur ^= 1;
        }
        // (last barrier of st-loop already issued; both buffers dead now)

        float b1v[4];
#pragma unroll
        for (int nf = 0; nf < 4; ++nf)
            b1v[nf] = b1[fc + 64 * wf + 16 * nf + l15];

#pragma unroll
        for (int h = 0; h < 2; ++h) {
            // ---- GELU: waves with wf==h write their 64 F cols (local 0..63) ----
            if (wf == h) {
#pragma unroll
                for (int mf = 0; mf < 4; ++mf)
#pragma unroll
                    for (int nf = 0; nf < 4; ++nf)
#pragma unroll
                        for (int r = 0; r < 4; ++r) {
                            const float v = acc[mf][nf][r] + b1v[nf];
                            const float gl = 0.5f * v * (1.0f + erff(v * 0.70710678118654752f));
                            _Float16 hh, hl;
                            f2h2(gl, hh, hl);
                            const int tok  = 64 * wr + 16 * mf + 4 * l4 + r;
                            const int fcol = 16 * nf + l15;   // local 0..63
                            hs_h[tok * HSS + fcol] = hh;
                            hs_l[tok * HSS + fcol] = hl;
                        }
            }
            __syncthreads();
            // ---- GEMM2 half h: MFMA, K=64 (R9/R18-validated scheme) ----
#pragma unroll
            for (int ks = 0; ks < 2; ++ks) {
                v8h vbh, vbl;
#pragma unroll
                for (int j = 0; j < 8; ++j) {
                    const float u = W2[(size_t)(fc + 64 * h + 32 * ks + 8 * l4 + j) * EDIM + l15];
                    _Float16 hh, hl;
                    f2h2(u, hh, hl);
                    vbh[j] = hh; vbl[j] = hl;
                }
#pragma unroll
                for (int mf2 = 0; mf2 < 2; ++mf2) {
                    const int aoff = (32 * w + 16 * mf2 + l15) * HSS + 32 * ks + 8 * l4;
                    const v8h vah = *(const v8h*)(hs_h + aoff);
                    const v8h val = *(const v8h*)(hs_l + aoff);
                    accL[mf2] = __builtin_amdgcn_mfma_f32_16x16x32_f16(vah, vbh, accL[mf2], 0, 0, 0);
                    accL[mf2] = __builtin_amdgcn_mfma_f32_16x16x32_f16(val, vbh, accL[mf2], 0, 0, 0);
                    accL[mf2] = __builtin_amdgcn_mfma_f32_16x16x32_f16(vah, vbl, accL[mf2], 0, 0, 0);
                }
            }
            if (h == 0) __syncthreads();   // half-1 GELU overwrites hs
        }
        // next fc's loop-top barrier protects hs before restaging
    }

    // ---- softmax + clip + top-2 + writes (R9/R18-proven mapping) ----
    float lg[8];
#pragma unroll
    for (int mf2 = 0; mf2 < 2; ++mf2)
#pragma unroll
        for (int r = 0; r < 4; ++r)
            lg[mf2 * 4 + r] = accL[mf2][r] + b2v;

    const int tx = l15;
#pragma unroll
    for (int i = 0; i < 8; ++i) {
        const int t = t0 + 32 * w + 16 * (i >> 2) + 4 * l4 + (i & 3);
        float mx = lg[i];
#pragma unroll
        for (int m = 1; m < 16; m <<= 1) mx = fmaxf(mx, __shfl_xor(mx, m, 64));
        float p = expf(lg[i] - mx);
        float s = p;
#pragma unroll
        for (int m = 1; m < 16; m <<= 1) s += __shfl_xor(s, m, 64);
        float pr = p / s;
        pr = fminf(fmaxf(pr, 1e-9f), 1.0f - 1e-9f);

        float v1 = pr; int i1 = tx;
#pragma unroll
        for (int m = 1; m < 16; m <<= 1) {
            const float vo = __shfl_xor(v1, m, 64);
            const int   io = __shfl_xor(i1, m, 64);
            if (vo > v1 || (vo == v1 && io < i1)) { v1 = vo; i1 = io; }
        }
        float v2 = (tx == i1) ? -1.0f : pr; int i2 = tx;
#pragma unroll
        for (int m = 1; m < 16; m <<= 1) {
            const float vo = __shfl_xor(v2, m, 64);
            const int   io = __shfl_xor(i2, m, 64);
            if (vo > v2 || (vo == v2 && io < i2)) { v2 = vo; i2 = io; }
        }
        const float rs = 1.0f / (v1 + v2);

        float* om  = out + (size_t)t * EDIM;
        float* orp = out + (size_t)NTOK * 18 + (size_t)t * EDIM;
        float* opf = out + (size_t)NTOK * 34 + (size_t)t * EDIM;
        om[tx]  = (tx == i1 || tx == i2) ? 1.0f : 0.0f;
        orp[tx] = (tx == i1) ? v1 * rs : ((tx == i2) ? v2 * rs : 0.0f);
        opf[tx] = pr;
        if (tx == 0) {
            float2* oi = (float2*)(out + (size_t)NTOK * 16 + (size_t)t * 2);
            *oi = make_float2((float)i1, (float)i2);
        }
    }
}

// ---------------- R15 fallback (verbatim), used if ws too small ----------------
#define XST  40
#define HST  68
#define FCHB 64
__global__ __launch_bounds__(256, 2)
void router_mfma7(const float* __restrict__ inp,
                  const float* __restrict__ cnd,
                  const float* __restrict__ W1,
                  const float* __restrict__ b1,
                  const float* __restrict__ W2,
                  const float* __restrict__ b2,
                  float* __restrict__ out)
{
    __shared__ __align__(16) char smem[34816];
    _Float16* xs_h = (_Float16*)(smem);
    _Float16* xs_l = (_Float16*)(smem + 10240);
    _Float16* ws_h = (_Float16*)(smem + 20480);
    _Float16* ws_l = (_Float16*)(smem + 25600);
    float*    hs   = (float*)(smem);

    const int tid  = threadIdx.x;
    const int lane = tid & 63;
    const int w    = tid >> 6;
    const int wr   = w >> 1;
    const int wc   = w & 1;
    const int l15  = lane & 15;
    const int l4   = lane >> 4;
    const int t0   = blockIdx.x * TBLK;
    const int ty   = tid >> 4;
    const int tx   = tid & 15;
    const int kq   = tid & 7;
    const int xr   = tid >> 3;
    const int fcl  = tid & 63;
    const int kg   = tid >> 6;

    float lg[8];
    { const float bb = b2[tx];
#pragma unroll
      for (int i = 0; i < 8; ++i) lg[i] = bb; }

    for (int fc = 0; fc < FDIM; fc += FCHB) {
        v4f acc[4][2];
#pragma unroll
        for (int mf = 0; mf < 4; ++mf)
#pragma unroll
            for (int nf = 0; nf < 2; ++nf) acc[mf][nf] = (v4f){0.f,0.f,0.f,0.f};

        for (int st = 0; st < 16; ++st) {
            const int kc = st * KST;
            __syncthreads();
            {
                const float* src = (kc < HDIM) ? (inp + (size_t)t0 * HDIM + kc)
                                               : (cnd + (size_t)t0 * HDIM + (kc - HDIM));
#pragma unroll
                for (int p = 0; p < 4; ++p) {
                    const int row = xr + 32 * p;
                    const float4 v = *(const float4*)(src + (size_t)row * HDIM + kq * 4);
                    _Float16 h0,l0,h1,l1,h2,l2,h3,l3;
                    f2h2(v.x,h0,l0); f2h2(v.y,h1,l1); f2h2(v.z,h2,l2); f2h2(v.w,h3,l3);
                    v4h hh, hl;
                    hh[0]=h0; hh[1]=h1; hh[2]=h2; hh[3]=h3;
                    hl[0]=l0; hl[1]=l1; hl[2]=l2; hl[3]=l3;
                    *(v4h*)(xs_h + row * XST + kq * 4) = hh;
                    *(v4h*)(xs_l + row * XST + kq * 4) = hl;
                }
            }
#pragma unroll
            for (int s = 0; s < 2; ++s) {
                const int kb = 4 * kg + 16 * s;
                const float u0 = W1[(size_t)(kc + kb + 0) * FDIM + fc + fcl];
                const float u1 = W1[(size_t)(kc + kb + 1) * FDIM + fc + fcl];
                const float u2 = W1[(size_t)(kc + kb + 2) * FDIM + fc + fcl];
                const float u3 = W1[(size_t)(kc + kb + 3) * FDIM + fc + fcl];
                _Float16 h0,l0,h1,l1,h2,l2,h3,l3;
                f2h2(u0,h0,l0); f2h2(u1,h1,l1); f2h2(u2,h2,l2); f2h2(u3,h3,l3);
                v4h hh, hl;
                hh[0]=h0; hh[1]=h1; hh[2]=h2; hh[3]=h3;
                hl[0]=l0; hl[1]=l1; hl[2]=l2; hl[3]=l3;
                *(v4h*)(ws_h + fcl * XST + kb) = hh;
                *(v4h*)(ws_l + fcl * XST + kb) = hl;
            }
            __syncthreads();
            {
                v8h bh[2], bl[2];
#pragma unroll
                for (int nf = 0; nf < 2; ++nf) {
                    const int off = (32 * wc + 16 * nf + l15) * XST + 8 * l4;
                    bh[nf] = *(const v8h*)(ws_h + off);
                    bl[nf] = *(const v8h*)(ws_l + off);
                }
#pragma unroll
                for (int mf = 0; mf < 4; ++mf) {
                    const int off = (64 * wr + 16 * mf + l15) * XST + 8 * l4;
                    const v8h ah = *(const v8h*)(xs_h + off);
                    const v8h al = *(const v8h*)(xs_l + off);
#pragma unroll
                    for (int nf = 0; nf < 2; ++nf) {
                        acc[mf][nf] = __builtin_amdgcn_mfma_f32_16x16x32_f16(ah, bh[nf], acc[mf][nf], 0, 0, 0);
                        acc[mf][nf] = __builtin_amdgcn_mfma_f32_16x16x32_f16(al, bh[nf], acc[mf][nf], 0, 0, 0);
                        acc[mf][nf] = __builtin_amdgcn_mfma_f32_16x16x32_f16(ah, bl[nf], acc[mf][nf], 0, 0, 0);
                    }
                }
            }
        }
        __syncthreads();
        {
            float b1v[2];
#pragma unroll
            for (int nf = 0; nf < 2; ++nf) b1v[nf] = b1[fc + 32 * wc + 16 * nf + l15];
#pragma unroll
            for (int mf = 0; mf < 4; ++mf)
#pragma unroll
                for (int nf = 0; nf < 2; ++nf)
#pragma unroll
                    for (int r = 0; r < 4; ++r) {
                        const float v = acc[mf][nf][r] + b1v[nf];
                        const int tok  = 64 * wr + 16 * mf + 4 * l4 + r;
                        const int fcol = 32 * wc + 16 * nf + l15;
                        hs[tok * HST + fcol] = 0.5f * v * (1.0f + erff(v * 0.70710678118654752f));
                    }
        }
        __syncthreads();
#pragma unroll
        for (int jb = 0; jb < 16; ++jb) {
            const int jbs = (jb + 4 * l4) & 15;
            float w2v[4];
#pragma unroll
            for (int j = 0; j < 4; ++j)
                w2v[j] = W2[(size_t)(fc + jbs * 4 + j) * EDIM + tx];
#pragma unroll
            for (int i = 0; i < 8; ++i) {
                const float4 hv = *(const float4*)(hs + (ty * 8 + i) * HST + jbs * 4);
                lg[i] = fmaf(hv.x, w2v[0], lg[i]);
                lg[i] = fmaf(hv.y, w2v[1], lg[i]);
                lg[i] = fmaf(hv.z, w2v[2], lg[i]);
                lg[i] = fmaf(hv.w, w2v[3], lg[i]);
            }
        }
    }
#pragma unroll
    for (int i = 0; i < 8; ++i) {
        const int t = t0 + ty * 8 + i;
        float mx = lg[i];
#pragma unroll
        for (int m = 1; m < 16; m <<= 1) mx = fmaxf(mx, __shfl_xor(mx, m, 64));
        float p = expf(lg[i] - mx);
        float s = p;
#pragma unroll
        for (int m = 1; m < 16; m <<= 1) s += __shfl_xor(s, m, 64);
        float pr = p / s;
        pr = fminf(fmaxf(pr, 1e-9f), 1.0f - 1e-9f);
        float v1 = pr; int i1 = tx;
#pragma unroll
        for (int m = 1; m < 16; m <<= 1) {
            const float vo = __shfl_xor(v1, m, 64);
            const int   io = __shfl_xor(i1, m, 64);
            if (vo > v1 || (vo == v1 && io < i1)) { v1 = vo; i1 = io; }
        }
        float v2 = (tx == i1) ? -1.0f : pr; int i2 = tx;
#pragma unroll
        for (int m = 1; m < 16; m <<= 1) {
            const float vo = __shfl_xor(v2, m, 64);
            const int   io = __shfl_xor(i2, m, 64);
            if (vo > v2 || (vo == v2 && io < i2)) { v2 = vo; i2 = io; }
        }
        const float rs = 1.0f / (v1 + v2);
        float* om  = out + (size_t)t * EDIM;
        float* orp = out + (size_t)NTOK * 18 + (size_t)t * EDIM;
        float* opf = out + (size_t)NTOK * 34 + (size_t)t * EDIM;
        om[tx]  = (tx == i1 || tx == i2) ? 1.0f : 0.0f;
        orp[tx] = (tx == i1) ? v1 * rs : ((tx == i2) ? v2 * rs : 0.0f);
        opf[tx] = pr;
        if (tx == 0) {
            float2* oi = (float2*)(out + (size_t)NTOK * 16 + (size_t)t * 2);
            *oi = make_float2((float)i1, (float)i2);
        }
    }
}

extern "C" void kernel_launch(void* const* d_in, const int* in_sizes, int n_in,
                              void* d_out, int out_size, void* d_ws, size_t ws_size,
                              hipStream_t stream)
{
    const float* inp = (const float*)d_in[0];
    const float* cnd = (const float*)d_in[1];
    const float* W1  = (const float*)d_in[2];
    const float* b1  = (const float*)d_in[3];
    const float* W2  = (const float*)d_in[4];
    const float* b2  = (const float*)d_in[5];
    float* out = (float*)d_out;

    if (ws_size >= WS_NEED) {
        char* wsb = (char*)d_ws;
        _Float16* xh  = (_Float16*)(wsb);
        _Float16* xl  = (_Float16*)(wsb + WS_XL);
        _Float16* w1h = (_Float16*)(wsb + WS_W1H);
        _Float16* w1l = (_Float16*)(wsb + WS_W1L);
        hipLaunchKernelGGL(prep_x, dim3(32768), dim3(256), 0, stream, inp, cnd, xh, xl);
        hipLaunchKernelGGL(prep_w1, dim3(256), dim3(256), 0, stream, W1, w1h, w1l);
        hipLaunchKernelGGL(router_mfma13, dim3(NTOK / TBLK), dim3(256), 0, stream,
                           xh, xl, w1h, w1l, b1, W2, b2, out);
    } else {
        hipLaunchKernelGGL(router_mfma7, dim3(NTOK / TBLK), dim3(256), 0, stream,
                           inp, cnd, W1, b1, W2, b2, out);
    }
}

// Round 22
// 627.550 us; speedup vs baseline: 2.8636x; 1.0082x over previous
//
#include <hip/hip_runtime.h>
#include <math.h>

#define NTOK 131072
#define HDIM 256
#define DDIM 512
#define FDIM 1024
#define EDIM 16
#define TBLK 128
#define FCH  128
#define KST  32
#define HSS  68    // hs f16 row stride (136 B)

// d_ws layout (bytes): xh frag-tiles @0 (134217728), xl @134217728,
// w1h frags @268435456 (1048576), w1l @269484032 (1048576),
// w2h frags @270532608 (32768), w2l @270565376 (32768) -> 270598144
#define WS_XL   134217728ULL
#define WS_W1H  268435456ULL
#define WS_W1L  269484032ULL
#define WS_W2H  270532608ULL
#define WS_W2L  270565376ULL
#define WS_NEED 270598144ULL

typedef __attribute__((ext_vector_type(8))) _Float16 v8h;
typedef __attribute__((ext_vector_type(4))) _Float16 v4h;
typedef __attribute__((ext_vector_type(4))) float v4f;

__device__ __forceinline__ void f2h2(float v, _Float16& h, _Float16& l) {
    h = (_Float16)v;
    l = (_Float16)(v - (float)h);
}

__device__ __forceinline__ void pack8(const float* u, v8h& hh, v8h& hl) {
    _Float16 h0,l0,h1,l1,h2,l2,h3,l3,h4,l4,h5,l5,h6,l6,h7,l7;
    f2h2(u[0],h0,l0); f2h2(u[1],h1,l1); f2h2(u[2],h2,l2); f2h2(u[3],h3,l3);
    f2h2(u[4],h4,l4); f2h2(u[5],h5,l5); f2h2(u[6],h6,l6); f2h2(u[7],h7,l7);
    hh[0]=h0; hh[1]=h1; hh[2]=h2; hh[3]=h3; hh[4]=h4; hh[5]=h5; hh[6]=h6; hh[7]=h7;
    hl[0]=l0; hl[1]=l1; hl[2]=l2; hl[3]=l3; hl[4]=l4; hl[5]=l5; hl[6]=l6; hl[7]=l7;
}

// async global->LDS, 16B per lane (linear dest = wave-uniform base + lane*16)
__device__ __forceinline__ void gl16(const void* g, void* l) {
    __builtin_amdgcn_global_load_lds(
        (const __attribute__((address_space(1))) void*)g,
        (__attribute__((address_space(3))) void*)l, 16, 0, 0);
}

// x -> f16 hi/lo, MFMA-A-fragment tile order (tile T=(tb,st): [frag][lane][8])
__global__ __launch_bounds__(256, 4)
void prep_x(const float* __restrict__ inp, const float* __restrict__ cnd,
            _Float16* __restrict__ xh, _Float16* __restrict__ xl)
{
    const size_t g = (size_t)blockIdx.x * 256 + threadIdx.x;
    const int lane = (int)(g & 63);
    const int fg   = (int)((g >> 6) & 7);
    const int T    = (int)(g >> 9);
    const int tb = T >> 4, st = T & 15;
    const int tok = tb * TBLK + fg * 16 + (lane & 15);
    const int k   = st * KST + (lane >> 4) * 8;
    const float* src = (k < HDIM) ? (inp + (size_t)tok * HDIM + k)
                                  : (cnd + (size_t)tok * HDIM + (k - HDIM));
    float u[8];
    *(float4*)&u[0] = *(const float4*)(src);
    *(float4*)&u[4] = *(const float4*)(src + 4);
    v8h hh, hl;
    pack8(u, hh, hl);
    *(v8h*)(xh + g * 8) = hh;
    *(v8h*)(xl + g * 8) = hl;
}

// W1 -> f16 hi/lo, MFMA-B-fragment order
__global__ __launch_bounds__(256, 4)
void prep_w1(const float* __restrict__ W1,
             _Float16* __restrict__ wh, _Float16* __restrict__ wl)
{
    const int g = blockIdx.x * 256 + threadIdx.x;
    const int lane = g & 63;
    const int K = (g >> 6) & 15;
    const int F = g >> 10;
    const int f  = F * 16 + (lane & 15);
    const int kb = K * KST + (lane >> 4) * 8;
    float u[8];
#pragma unroll
    for (int e = 0; e < 8; ++e)
        u[e] = W1[(size_t)(kb + e) * FDIM + f];
    v8h hh, hl;
    pack8(u, hh, hl);
    *(v8h*)(wh + (size_t)g * 8) = hh;
    *(v8h*)(wl + (size_t)g * 8) = hl;
}

// W2 -> f16 hi/lo, GEMM2-B-fragment order:
// slot g (0..2047): lane=g&63, Kslice=g>>6 (0..31);
// expert = lane&15; k = Kslice*32 + (lane>>4)*8 + j
__global__ __launch_bounds__(256, 4)
void prep_w2(const float* __restrict__ W2,
             _Float16* __restrict__ wh, _Float16* __restrict__ wl)
{
    const int g = blockIdx.x * 256 + threadIdx.x;   // 0..2047
    const int lane = g & 63;
    const int Ks = g >> 6;
    const int e  = lane & 15;
    const int kb = Ks * 32 + (lane >> 4) * 8;
    float u[8];
#pragma unroll
    for (int j = 0; j < 8; ++j)
        u[j] = W2[(size_t)(kb + j) * EDIM + e];
    v8h hh, hl;
    pack8(u, hh, hl);
    *(v8h*)(wh + (size_t)g * 8) = hh;
    *(v8h*)(wl + (size_t)g * 8) = hl;
}

// stage one (x, W1) tile pair into LDS buffer b (8 async 16B loads / thread)
__device__ __forceinline__ void stage_tiles(char* smem, int b, int tid,
        const _Float16* xh, const _Float16* xl,
        const _Float16* w1h, const _Float16* w1l,
        int blk, int fc, int st)
{
    char* base = smem + b * 32768;
    const char* sh = (const char*)(xh + ((size_t)blk * 16 + st) * 4096);
    const char* sl = (const char*)(xl + ((size_t)blk * 16 + st) * 4096);
    gl16(sh + tid * 16,        base + tid * 16);
    gl16(sh + tid * 16 + 4096, base + tid * 16 + 4096);
    gl16(sl + tid * 16,        base + 8192 + tid * 16);
    gl16(sl + tid * 16 + 4096, base + 8192 + tid * 16 + 4096);
    const size_t wb0 = (((size_t)((fc >> 4) + (tid >> 6)) * 16 + st) * 64
                        + (tid & 63)) * 16;
    const size_t wb1 = (((size_t)((fc >> 4) + 4 + (tid >> 6)) * 16 + st) * 64
                        + (tid & 63)) * 16;
    gl16((const char*)w1h + wb0, base + 16384 + tid * 16);
    gl16((const char*)w1h + wb1, base + 16384 + tid * 16 + 4096);
    gl16((const char*)w1l + wb0, base + 24576 + tid * 16);
    gl16((const char*)w1l + wb1, base + 24576 + tid * 16 + 4096);
}

// Main: R21 dbuf + T4 counted vmcnt: after issuing next tile's 8 loads, wait
// vmcnt(8) (current tile's 8 = oldest, done) -> raw s_barrier. Prefetch stays
// in flight ACROSS the barrier; never drain to 0 in the loop (except st=15).
// Every wave waits for its own loads before its barrier -> after barrier all
// 32KB resident. Second raw barrier after MFMA protects buf vs next overwrite.
__global__ __launch_bounds__(256, 2)
void router_mfma14(const _Float16* __restrict__ xh, const _Float16* __restrict__ xl,
                   const _Float16* __restrict__ w1h, const _Float16* __restrict__ w1l,
                   const _Float16* __restrict__ w2h, const _Float16* __restrict__ w2l,
                   const float* __restrict__ b1,
                   const float* __restrict__ b2,
                   float* __restrict__ out)
{
    __shared__ __align__(16) char smem[65536];
    _Float16* hs_h = (_Float16*)(smem);            // alias buf0, barrier-separated
    _Float16* hs_l = (_Float16*)(smem + 17408);

    const int tid  = threadIdx.x;
    const int lane = tid & 63;
    const int w    = tid >> 6;        // wave 0..3
    const int wr   = w >> 1;          // token half (64)
    const int wf   = w & 1;           // F half (64 of the 128-chunk)
    const int l15  = lane & 15;
    const int l4   = lane >> 4;
    const int t0   = blockIdx.x * TBLK;

    const float b2v = b2[l15];
    v4f accL[2] = {{0.f,0.f,0.f,0.f},{0.f,0.f,0.f,0.f}};

    for (int fc = 0; fc < FDIM; fc += FCH) {
        v4f acc[4][4];
#pragma unroll
        for (int mf = 0; mf < 4; ++mf)
#pragma unroll
            for (int nf = 0; nf < 4; ++nf)
                acc[mf][nf] = (v4f){0.f,0.f,0.f,0.f};

        __syncthreads();   // prior GEMM2 hs reads (fc>0) complete
        stage_tiles(smem, 0, tid, xh, xl, w1h, w1l, blockIdx.x, fc, 0);

        int cur = 0;
        for (int st = 0; st < 16; ++st) {
            if (st < 15) {
                stage_tiles(smem, cur ^ 1, tid, xh, xl, w1h, w1l,
                            blockIdx.x, fc, st + 1);          // +8 -> 16 in flight
                asm volatile("s_waitcnt vmcnt(8)" ::: "memory"); // cur tile landed
            } else {
                asm volatile("s_waitcnt vmcnt(0)" ::: "memory"); // full drain, last
            }
            __builtin_amdgcn_s_barrier();   // all waves: buf[cur] resident
            // ---- MFMA 16x16x32 f16 on buf[cur]: A resident, B streamed ----
            {
                const _Float16* xs_h = (const _Float16*)(smem + cur * 32768);
                const _Float16* xs_l = (const _Float16*)(smem + cur * 32768 + 8192);
                const _Float16* ws_h = (const _Float16*)(smem + cur * 32768 + 16384);
                const _Float16* ws_l = (const _Float16*)(smem + cur * 32768 + 24576);
                v8h ah[4], al[4];
#pragma unroll
                for (int mf = 0; mf < 4; ++mf) {
                    const int aoff = ((4 * wr + mf) * 64 + lane) * 8;
                    ah[mf] = *(const v8h*)(xs_h + aoff);
                    al[mf] = *(const v8h*)(xs_l + aoff);
                }
#pragma unroll
                for (int nf = 0; nf < 4; ++nf) {
                    const int boff = ((4 * wf + nf) * 64 + lane) * 8;
                    const v8h bh = *(const v8h*)(ws_h + boff);
                    const v8h bl = *(const v8h*)(ws_l + boff);
#pragma unroll
                    for (int mf = 0; mf < 4; ++mf) {
                        acc[mf][nf] = __builtin_amdgcn_mfma_f32_16x16x32_f16(ah[mf], bh, acc[mf][nf], 0, 0, 0);
                        acc[mf][nf] = __builtin_amdgcn_mfma_f32_16x16x32_f16(al[mf], bh, acc[mf][nf], 0, 0, 0);
                        acc[mf][nf] = __builtin_amdgcn_mfma_f32_16x16x32_f16(ah[mf], bl, acc[mf][nf], 0, 0, 0);
                    }
                }
            }
            __builtin_amdgcn_s_barrier();   // buf[cur] reads done before overwrite
            cur ^= 1;
        }
        // st=15 drained vmcnt(0); last barrier passed; both buffers dead

        float b1v[4];
#pragma unroll
        for (int nf = 0; nf < 4; ++nf)
            b1v[nf] = b1[fc + 64 * wf + 16 * nf + l15];

#pragma unroll
        for (int h = 0; h < 2; ++h) {
            // ---- GELU: waves with wf==h write their 64 F cols (local 0..63) ----
            if (wf == h) {
#pragma unroll
                for (int mf = 0; mf < 4; ++mf)
#pragma unroll
                    for (int nf = 0; nf < 4; ++nf)
#pragma unroll
                        for (int r = 0; r < 4; ++r) {
                            const float v = acc[mf][nf][r] + b1v[nf];
                            const float gl = 0.5f * v * (1.0f + erff(v * 0.70710678118654752f));
                            _Float16 hh, hl;
                            f2h2(gl, hh, hl);
                            const int tok  = 64 * wr + 16 * mf + 4 * l4 + r;
                            const int fcol = 16 * nf + l15;   // local 0..63
                            hs_h[tok * HSS + fcol] = hh;
                            hs_l[tok * HSS + fcol] = hl;
                        }
            }
            __syncthreads();
            // ---- GEMM2 half h: MFMA, K=64; B pre-packed (w2h/w2l frags) ----
#pragma unroll
            for (int ks = 0; ks < 2; ++ks) {
                const size_t Ks = (size_t)((fc + 64 * h + 32 * ks) >> 5);
                const v8h vbh = *(const v8h*)(w2h + (Ks * 64 + lane) * 8);
                const v8h vbl = *(const v8h*)(w2l + (Ks * 64 + lane) * 8);
#pragma unroll
                for (int mf2 = 0; mf2 < 2; ++mf2) {
                    const int aoff = (32 * w + 16 * mf2 + l15) * HSS + 32 * ks + 8 * l4;
                    const v8h vah = *(const v8h*)(hs_h + aoff);
                    const v8h val = *(const v8h*)(hs_l + aoff);
                    accL[mf2] = __builtin_amdgcn_mfma_f32_16x16x32_f16(vah, vbh, accL[mf2], 0, 0, 0);
                    accL[mf2] = __builtin_amdgcn_mfma_f32_16x16x32_f16(val, vbh, accL[mf2], 0, 0, 0);
                    accL[mf2] = __builtin_amdgcn_mfma_f32_16x16x32_f16(vah, vbl, accL[mf2], 0, 0, 0);
                }
            }
            if (h == 0) __syncthreads();   // half-1 GELU overwrites hs
        }
        // next fc's loop-top __syncthreads protects hs before restaging
    }

    // ---- softmax + clip + top-2 + writes (R9/R18-proven mapping) ----
    float lg[8];
#pragma unroll
    for (int mf2 = 0; mf2 < 2; ++mf2)
#pragma unroll
        for (int r = 0; r < 4; ++r)
            lg[mf2 * 4 + r] = accL[mf2][r] + b2v;

    const int tx = l15;
#pragma unroll
    for (int i = 0; i < 8; ++i) {
        const int t = t0 + 32 * w + 16 * (i >> 2) + 4 * l4 + (i & 3);
        float mx = lg[i];
#pragma unroll
        for (int m = 1; m < 16; m <<= 1) mx = fmaxf(mx, __shfl_xor(mx, m, 64));
        float p = expf(lg[i] - mx);
        float s = p;
#pragma unroll
        for (int m = 1; m < 16; m <<= 1) s += __shfl_xor(s, m, 64);
        float pr = p / s;
        pr = fminf(fmaxf(pr, 1e-9f), 1.0f - 1e-9f);

        float v1 = pr; int i1 = tx;
#pragma unroll
        for (int m = 1; m < 16; m <<= 1) {
            const float vo = __shfl_xor(v1, m, 64);
            const int   io = __shfl_xor(i1, m, 64);
            if (vo > v1 || (vo == v1 && io < i1)) { v1 = vo; i1 = io; }
        }
        float v2 = (tx == i1) ? -1.0f : pr; int i2 = tx;
#pragma unroll
        for (int m = 1; m < 16; m <<= 1) {
            const float vo = __shfl_xor(v2, m, 64);
            const int   io = __shfl_xor(i2, m, 64);
            if (vo > v2 || (vo == v2 && io < i2)) { v2 = vo; i2 = io; }
        }
        const float rs = 1.0f / (v1 + v2);

        float* om  = out + (size_t)t * EDIM;
        float* orp = out + (size_t)NTOK * 18 + (size_t)t * EDIM;
        float* opf = out + (size_t)NTOK * 34 + (size_t)t * EDIM;
        om[tx]  = (tx == i1 || tx == i2) ? 1.0f : 0.0f;
        orp[tx] = (tx == i1) ? v1 * rs : ((tx == i2) ? v2 * rs : 0.0f);
        opf[tx] = pr;
        if (tx == 0) {
            float2* oi = (float2*)(out + (size_t)NTOK * 16 + (size_t)t * 2);
            *oi = make_float2((float)i1, (float)i2);
        }
    }
}

// ---------------- R15 fallback (verbatim), used if ws too small ----------------
#define XST  40
#define HST  68
#define FCHB 64
__global__ __launch_bounds__(256, 2)
void router_mfma7(const float* __restrict__ inp,
                  const float* __restrict__ cnd,
                  const float* __restrict__ W1,
                  const float* __restrict__ b1,
                  const float* __restrict__ W2,
                  const float* __restrict__ b2,
                  float* __restrict__ out)
{
    __shared__ __align__(16) char smem[34816];
    _Float16* xs_h = (_Float16*)(smem);
    _Float16* xs_l = (_Float16*)(smem + 10240);
    _Float16* ws_h = (_Float16*)(smem + 20480);
    _Float16* ws_l = (_Float16*)(smem + 25600);
    float*    hs   = (float*)(smem);

    const int tid  = threadIdx.x;
    const int lane = tid & 63;
    const int w    = tid >> 6;
    const int wr   = w >> 1;
    const int wc   = w & 1;
    const int l15  = lane & 15;
    const int l4   = lane >> 4;
    const int t0   = blockIdx.x * TBLK;
    const int ty   = tid >> 4;
    const int tx   = tid & 15;
    const int kq   = tid & 7;
    const int xr   = tid >> 3;
    const int fcl  = tid & 63;
    const int kg   = tid >> 6;

    float lg[8];
    { const float bb = b2[tx];
#pragma unroll
      for (int i = 0; i < 8; ++i) lg[i] = bb; }

    for (int fc = 0; fc < FDIM; fc += FCHB) {
        v4f acc[4][2];
#pragma unroll
        for (int mf = 0; mf < 4; ++mf)
#pragma unroll
            for (int nf = 0; nf < 2; ++nf) acc[mf][nf] = (v4f){0.f,0.f,0.f,0.f};

        for (int st = 0; st < 16; ++st) {
            const int kc = st * KST;
            __syncthreads();
            {
                const float* src = (kc < HDIM) ? (inp + (size_t)t0 * HDIM + kc)
                                               : (cnd + (size_t)t0 * HDIM + (kc - HDIM));
#pragma unroll
                for (int p = 0; p < 4; ++p) {
                    const int row = xr + 32 * p;
                    const float4 v = *(const float4*)(src + (size_t)row * HDIM + kq * 4);
                    _Float16 h0,l0,h1,l1,h2,l2,h3,l3;
                    f2h2(v.x,h0,l0); f2h2(v.y,h1,l1); f2h2(v.z,h2,l2); f2h2(v.w,h3,l3);
                    v4h hh, hl;
                    hh[0]=h0; hh[1]=h1; hh[2]=h2; hh[3]=h3;
                    hl[0]=l0; hl[1]=l1; hl[2]=l2; hl[3]=l3;
                    *(v4h*)(xs_h + row * XST + kq * 4) = hh;
                    *(v4h*)(xs_l + row * XST + kq * 4) = hl;
                }
            }
#pragma unroll
            for (int s = 0; s < 2; ++s) {
                const int kb = 4 * kg + 16 * s;
                const float u0 = W1[(size_t)(kc + kb + 0) * FDIM + fc + fcl];
                const float u1 = W1[(size_t)(kc + kb + 1) * FDIM + fc + fcl];
                const float u2 = W1[(size_t)(kc + kb + 2) * FDIM + fc + fcl];
                const float u3 = W1[(size_t)(kc + kb + 3) * FDIM + fc + fcl];
                _Float16 h0,l0,h1,l1,h2,l2,h3,l3;
                f2h2(u0,h0,l0); f2h2(u1,h1,l1); f2h2(u2,h2,l2); f2h2(u3,h3,l3);
                v4h hh, hl;
                hh[0]=h0; hh[1]=h1; hh[2]=h2; hh[3]=h3;
                hl[0]=l0; hl[1]=l1; hl[2]=l2; hl[3]=l3;
                *(v4h*)(ws_h + fcl * XST + kb) = hh;
                *(v4h*)(ws_l + fcl * XST + kb) = hl;
            }
            __syncthreads();
            {
                v8h bh[2], bl[2];
#pragma unroll
                for (int nf = 0; nf < 2; ++nf) {
                    const int off = (32 * wc + 16 * nf + l15) * XST + 8 * l4;
                    bh[nf] = *(const v8h*)(ws_h + off);
                    bl[nf] = *(const v8h*)(ws_l + off);
                }
#pragma unroll
                for (int mf = 0; mf < 4; ++mf) {
                    const int off = (64 * wr + 16 * mf + l15) * XST + 8 * l4;
                    const v8h ah = *(const v8h*)(xs_h + off);
                    const v8h al = *(const v8h*)(xs_l + off);
#pragma unroll
                    for (int nf = 0; nf < 2; ++nf) {
                        acc[mf][nf] = __builtin_amdgcn_mfma_f32_16x16x32_f16(ah, bh[nf], acc[mf][nf], 0, 0, 0);
                        acc[mf][nf] = __builtin_amdgcn_mfma_f32_16x16x32_f16(al, bh[nf], acc[mf][nf], 0, 0, 0);
                        acc[mf][nf] = __builtin_amdgcn_mfma_f32_16x16x32_f16(ah, bl[nf], acc[mf][nf], 0, 0, 0);
                    }
                }
            }
        }
        __syncthreads();
        {
            float b1v[2];
#pragma unroll
            for (int nf = 0; nf < 2; ++nf) b1v[nf] = b1[fc + 32 * wc + 16 * nf + l15];
#pragma unroll
            for (int mf = 0; mf < 4; ++mf)
#pragma unroll
                for (int nf = 0; nf < 2; ++nf)
#pragma unroll
                    for (int r = 0; r < 4; ++r) {
                        const float v = acc[mf][nf][r] + b1v[nf];
                        const int tok  = 64 * wr + 16 * mf + 4 * l4 + r;
                        const int fcol = 32 * wc + 16 * nf + l15;
                        hs[tok * HST + fcol] = 0.5f * v * (1.0f + erff(v * 0.70710678118654752f));
                    }
        }
        __syncthreads();
#pragma unroll
        for (int jb = 0; jb < 16; ++jb) {
            const int jbs = (jb + 4 * l4) & 15;
            float w2v[4];
#pragma unroll
            for (int j = 0; j < 4; ++j)
                w2v[j] = W2[(size_t)(fc + jbs * 4 + j) * EDIM + tx];
#pragma unroll
            for (int i = 0; i < 8; ++i) {
                const float4 hv = *(const float4*)(hs + (ty * 8 + i) * HST + jbs * 4);
                lg[i] = fmaf(hv.x, w2v[0], lg[i]);
                lg[i] = fmaf(hv.y, w2v[1], lg[i]);
                lg[i] = fmaf(hv.z, w2v[2], lg[i]);
                lg[i] = fmaf(hv.w, w2v[3], lg[i]);
            }
        }
    }
#pragma unroll
    for (int i = 0; i < 8; ++i) {
        const int t = t0 + ty * 8 + i;
        float mx = lg[i];
#pragma unroll
        for (int m = 1; m < 16; m <<= 1) mx = fmaxf(mx, __shfl_xor(mx, m, 64));
        float p = expf(lg[i] - mx);
        float s = p;
#pragma unroll
        for (int m = 1; m < 16; m <<= 1) s += __shfl_xor(s, m, 64);
        float pr = p / s;
        pr = fminf(fmaxf(pr, 1e-9f), 1.0f - 1e-9f);
        float v1 = pr; int i1 = tx;
#pragma unroll
        for (int m = 1; m < 16; m <<= 1) {
            const float vo = __shfl_xor(v1, m, 64);
            const int   io = __shfl_xor(i1, m, 64);
            if (vo > v1 || (vo == v1 && io < i1)) { v1 = vo; i1 = io; }
        }
        float v2 = (tx == i1) ? -1.0f : pr; int i2 = tx;
#pragma unroll
        for (int m = 1; m < 16; m <<= 1) {
            const float vo = __shfl_xor(v2, m, 64);
            const int   io = __shfl_xor(i2, m, 64);
            if (vo > v2 || (vo == v2 && io < i2)) { v2 = vo; i2 = io; }
        }
        const float rs = 1.0f / (v1 + v2);
        float* om  = out + (size_t)t * EDIM;
        float* orp = out + (size_t)NTOK * 18 + (size_t)t * EDIM;
        float* opf = out + (size_t)NTOK * 34 + (size_t)t * EDIM;
        om[tx]  = (tx == i1 || tx == i2) ? 1.0f : 0.0f;
        orp[tx] = (tx == i1) ? v1 * rs : ((tx == i2) ? v2 * rs : 0.0f);
        opf[tx] = pr;
        if (tx == 0) {
            float2* oi = (float2*)(out + (size_t)NTOK * 16 + (size_t)t * 2);
            *oi = make_float2((float)i1, (float)i2);
        }
    }
}

extern "C" void kernel_launch(void* const* d_in, const int* in_sizes, int n_in,
                              void* d_out, int out_size, void* d_ws, size_t ws_size,
                              hipStream_t stream)
{
    const float* inp = (const float*)d_in[0];
    const float* cnd = (const float*)d_in[1];
    const float* W1  = (const float*)d_in[2];
    const float* b1  = (const float*)d_in[3];
    const float* W2  = (const float*)d_in[4];
    const float* b2  = (const float*)d_in[5];
    float* out = (float*)d_out;

    if (ws_size >= WS_NEED) {
        char* wsb = (char*)d_ws;
        _Float16* xh  = (_Float16*)(wsb);
        _Float16* xl  = (_Float16*)(wsb + WS_XL);
        _Float16* w1h = (_Float16*)(wsb + WS_W1H);
        _Float16* w1l = (_Float16*)(wsb + WS_W1L);
        _Float16* w2h = (_Float16*)(wsb + WS_W2H);
        _Float16* w2l = (_Float16*)(wsb + WS_W2L);
        hipLaunchKernelGGL(prep_x, dim3(32768), dim3(256), 0, stream, inp, cnd, xh, xl);
        hipLaunchKernelGGL(prep_w1, dim3(256), dim3(256), 0, stream, W1, w1h, w1l);
        hipLaunchKernelGGL(prep_w2, dim3(8), dim3(256), 0, stream, W2, w2h, w2l);
        hipLaunchKernelGGL(router_mfma14, dim3(NTOK / TBLK), dim3(256), 0, stream,
                           xh, xl, w1h, w1l, w2h, w2l, b1, b2, out);
    } else {
        hipLaunchKernelGGL(router_mfma7, dim3(NTOK / TBLK), dim3(256), 0, stream,
                           inp, cnd, W1, b1, W2, b2, out);
    }
}